// Round 3
// baseline (203.367 us; speedup 1.0000x reference)
//
#include <hip/hip_runtime.h>

#define HW    96
#define NPIX  9216        // 96*96
#define NCH   64          // C
#define INNER 3
#define NDIL  3
#define BB    2           // batch
#define TOTPIX (BB * NPIX)   // 18432

typedef __attribute__((ext_vector_type(8))) short short8;            // 8 bf16
typedef __attribute__((ext_vector_type(8))) unsigned short ushort8;  // 8 bf16 raw
typedef __attribute__((ext_vector_type(4))) float f32x4;

__device__ __forceinline__ ushort f2bf_rne(float f) {
    unsigned u = __float_as_uint(f);
    u += 0x7fffu + ((u >> 16) & 1u);
    return (ushort)(u >> 16);
}
__device__ __forceinline__ float bf2f(ushort u) {
    return __uint_as_float((unsigned)u << 16);
}
// pack hi16(a),hi16(b) -> dword {bf16(b)<<16 | bf16(a)} (trunc; ratio-safe for P)
__device__ __forceinline__ unsigned pack_bf(float lo, float hi) {
    return __builtin_amdgcn_perm(__float_as_uint(hi), __float_as_uint(lo), 0x07060302u);
}

// ---------------------------------------------------------------------------
// Kernel 1: x_red = 1x1 conv (64 -> 3 channels)
// ---------------------------------------------------------------------------
__global__ void k_reduce(const float* __restrict__ x, const float* __restrict__ w_red,
                         const float* __restrict__ b_red, float* __restrict__ xred) {
    int pix = blockIdx.x * blockDim.x + threadIdx.x;
    if (pix >= TOTPIX) return;
    int b = pix / NPIX, n = pix % NPIX;
    float a0 = b_red[0], a1 = b_red[1], a2 = b_red[2];
    const float* xb = x + (size_t)b * NCH * NPIX + n;
    #pragma unroll
    for (int c = 0; c < NCH; ++c) {
        float xv = xb[(size_t)c * NPIX];
        a0 = fmaf(w_red[0 * NCH + c], xv, a0);
        a1 = fmaf(w_red[1 * NCH + c], xv, a1);
        a2 = fmaf(w_red[2 * NCH + c], xv, a2);
    }
    float* xr = xred + (size_t)b * INNER * NPIX + n;
    xr[0 * NPIX] = a0; xr[1 * NPIX] = a1; xr[2 * NPIX] = a2;
}

// ---------------------------------------------------------------------------
// Kernel 2a: features. thread = (pixel, dilation i3). Writes FT[j][pix] bf16,
// j = i3*18 + t*3 + o. Rows 54..63 never written — zero-weighted in k_fuse.
// ---------------------------------------------------------------------------
__global__ __launch_bounds__(256) void
k_feat(const float* __restrict__ xred, const float* __restrict__ w_dil,
       const float* __restrict__ b_dil, ushort* __restrict__ FT) {
    int gid = blockIdx.x * 256 + threadIdx.x;      // 3 * 18432 threads
    int i3 = gid / TOTPIX;                          // wave-uniform
    int pix = gid - i3 * TOTPIX;
    int b = pix / NPIX, n = pix % NPIX;
    int h = n / HW, w = n % HW;
    const float* xr = xred + (size_t)b * INNER * NPIX;
    int d = i3 + 1;

    float co[3] = {b_dil[i3 * 3 + 0], b_dil[i3 * 3 + 1], b_dil[i3 * 3 + 2]};
    #pragma unroll
    for (int ci = 0; ci < 3; ++ci) {
        const float* xo = xr + ci * NPIX;
        #pragma unroll
        for (int kh = 0; kh < 3; ++kh) {
            int hh = h + (kh - 1) * d;
            #pragma unroll
            for (int kw = 0; kw < 3; ++kw) {
                int ww = w + (kw - 1) * d;
                float v = ((unsigned)hh < HW && (unsigned)ww < HW) ? xo[hh * HW + ww] : 0.f;
                #pragma unroll
                for (int o = 0; o < 3; ++o)
                    co[o] = fmaf(w_dil[(9 * i3 + 3 * o + ci) * 9 + kh * 3 + kw], v, co[o]);
            }
        }
    }

    float tf[6][3];
    #pragma unroll
    for (int o = 0; o < 3; ++o) {
        const float* xo = xr + o * NPIX;
        tf[0][o] = xo[h * HW + w];
        tf[1][o] = xo[h * HW + (HW - 1 - w)];
        tf[2][o] = xo[(HW - 1 - h) * HW + w];
        tf[3][o] = xo[w * HW + (HW - 1 - h)];
        tf[4][o] = xo[(HW - 1 - h) * HW + (HW - 1 - w)];
        tf[5][o] = xo[(HW - 1 - w) * HW + h];
    }

    #pragma unroll
    for (int t = 0; t < 6; ++t)
        #pragma unroll
        for (int o = 0; o < 3; ++o) {
            int j = i3 * 18 + t * 3 + o;
            FT[(size_t)j * TOTPIX + pix] = f2bf_rne(co[o] * tf[t][o]);
        }
}

// ---------------------------------------------------------------------------
// Kernel 2b: fuse conv as MFMA GEMM, 64 px/block (grid 288).
// ---------------------------------------------------------------------------
__global__ __launch_bounds__(256) void
k_fuse(const ushort* __restrict__ FT, const float* __restrict__ w_fuse,
       const float* __restrict__ b_fuse, ushort* __restrict__ tok,
       ushort* __restrict__ tokT) {
    __shared__ ushort wpad[64 * 72];     // [c][j pad 72]
    __shared__ float  bsh[64];
    __shared__ ushort tile[64 * 72];     // [c][64 px + 8 pad]

    int tid = threadIdx.x;
    for (int i = tid; i < 64 * 64; i += 256) {
        int c = i >> 6, j = i & 63;
        wpad[c * 72 + j] = (j < 54) ? f2bf_rne(w_fuse[c * 54 + j]) : (ushort)0;
    }
    if (tid < 64) bsh[tid] = b_fuse[tid];
    __syncthreads();

    int wv = tid >> 6, lane = tid & 63, quad = lane >> 4, l15 = lane & 15;
    int px0 = blockIdx.x * 64;

    short8 af[4][2];
    #pragma unroll
    for (int m = 0; m < 4; ++m)
        #pragma unroll
        for (int kc = 0; kc < 2; ++kc)
            af[m][kc] = *(const short8*)&wpad[(16 * m + l15) * 72 + quad * 8 + 32 * kc];

    f32x4 acc[4];
    #pragma unroll
    for (int m = 0; m < 4; ++m) acc[m] = (f32x4){0.f, 0.f, 0.f, 0.f};

    int px = px0 + wv * 16 + l15;
    #pragma unroll
    for (int kc = 0; kc < 2; ++kc) {
        short8 bf;
        #pragma unroll
        for (int jj = 0; jj < 8; ++jj)
            bf[jj] = (short)FT[(size_t)(quad * 8 + jj + 32 * kc) * TOTPIX + px];
        #pragma unroll
        for (int m = 0; m < 4; ++m)
            acc[m] = __builtin_amdgcn_mfma_f32_16x16x32_bf16(af[m][kc], bf, acc[m], 0, 0, 0);
    }

    #pragma unroll
    for (int m = 0; m < 4; ++m)
        #pragma unroll
        for (int r = 0; r < 4; ++r) {
            int c = 16 * m + quad * 4 + r;
            tile[c * 72 + wv * 16 + l15] = f2bf_rne(acc[m][r] + bsh[c]);
        }
    __syncthreads();

    int b0 = px0 / NPIX, n0 = px0 % NPIX;
    {   // tok[b][n][c]
        int lp = tid >> 2, part = tid & 3;
        ushort row[16];
        #pragma unroll
        for (int k = 0; k < 16; ++k) row[k] = tile[(part * 16 + k) * 72 + lp];
        ushort* dst = tok + ((size_t)b0 * NPIX + n0 + lp) * NCH + part * 16;
        *(ushort8*)&dst[0] = *(const ushort8*)&row[0];
        *(ushort8*)&dst[8] = *(const ushort8*)&row[8];
    }
    {   // tokT[b][c][n]
        int c = tid >> 2, seg = tid & 3;
        ushort* dst = tokT + ((size_t)b0 * NCH + c) * NPIX + n0 + seg * 16;
        *(ushort8*)&dst[0] = *(const ushort8*)&tile[c * 72 + seg * 16];
        *(ushort8*)&dst[8] = *(const ushort8*)&tile[c * 72 + seg * 16 + 8];
    }
}

// ---------------------------------------------------------------------------
// Kernel 3 helpers (R2 pipelined structure, kept: it improved per-block
// throughput 40 -> 28 µs per 576 keys). R3 adds: pt LDS double-buffer
// (removes WAR ordering between body i reads and body i+1 writes).
// ---------------------------------------------------------------------------
__device__ __forceinline__ void attn_loadK(const ushort* __restrict__ tb, int kbase,
                                           int l15, int quad, short8 (&kd)[4]) {
    #pragma unroll
    for (int m2 = 0; m2 < 2; ++m2) {
        const ushort* kr = tb + (size_t)(kbase + 16 * m2 + l15) * NCH + quad * 8;
        kd[2 * m2 + 0] = *(const short8*)(kr + 0);
        kd[2 * m2 + 1] = *(const short8*)(kr + 32);
    }
}

__device__ __forceinline__ void attn_body(const ushort* __restrict__ tbT, int kbase,
                                          int l15, int quad, ushort* __restrict__ ptw,
                                          const short8 (&qf)[4][2], const short8 (&kd)[4],
                                          f32x4 (&O)[4][4], float (&lrun)[4]) {
    const float FM = 16.0f;             // fixed exp2-domain shift

    // V^T fragments (A[ch][key]) direct from tokT — issued first, used last
    short8 vf[4];
    #pragma unroll
    for (int mc = 0; mc < 4; ++mc)
        vf[mc] = *(const short8*)(tbT + (size_t)(16 * mc + l15) * NPIX + kbase + quad * 8);

    // S^T 32-key step: D[key][q]; A rows (keys) from prefetched kd
    f32x4 S[2][4];
    #pragma unroll
    for (int m = 0; m < 2; ++m)
        #pragma unroll
        for (int n = 0; n < 4; ++n) S[m][n] = (f32x4){0.f, 0.f, 0.f, 0.f};

    __builtin_amdgcn_s_setprio(1);
    #pragma unroll
    for (int m2 = 0; m2 < 2; ++m2)
        #pragma unroll
        for (int cc = 0; cc < 2; ++cc)
            #pragma unroll
            for (int n = 0; n < 4; ++n)
                S[m2][n] = __builtin_amdgcn_mfma_f32_16x16x32_bf16(kd[2 * m2 + cc],
                                                                   qf[n][cc], S[m2][n],
                                                                   0, 0, 0);
    __builtin_amdgcn_s_setprio(0);

    // softmax numerators, fixed base: p = exp2(s - FM). ALL writes batched.
    #pragma unroll
    for (int n = 0; n < 4; ++n) {
        int q = 16 * n + l15;
        #pragma unroll
        for (int m2 = 0; m2 < 2; ++m2) {
            float p0 = __builtin_amdgcn_exp2f(S[m2][n][0] - FM);
            float p1 = __builtin_amdgcn_exp2f(S[m2][n][1] - FM);
            float p2 = __builtin_amdgcn_exp2f(S[m2][n][2] - FM);
            float p3 = __builtin_amdgcn_exp2f(S[m2][n][3] - FM);
            lrun[n] += (p0 + p1) + (p2 + p3);
            uint2 wd = make_uint2(pack_bf(p0, p1), pack_bf(p2, p3));
            // key_local = 16*m2 + quad*4 + reg
            *(uint2*)&ptw[q * 40 + m2 * 16 + quad * 4] = wd;
        }
    }

    // O^T += V^T·P^T (K=32): batched reads + MFMAs (same-wave pt region)
    __builtin_amdgcn_s_setprio(1);
    #pragma unroll
    for (int n = 0; n < 4; ++n) {
        short8 bfr = *(const short8*)&ptw[(16 * n + l15) * 40 + quad * 8];
        #pragma unroll
        for (int mc = 0; mc < 4; ++mc)
            O[mc][n] = __builtin_amdgcn_mfma_f32_16x16x32_bf16(vf[mc], bfr,
                                                               O[mc][n], 0, 0, 0);
    }
    __builtin_amdgcn_s_setprio(0);
}

// ---------------------------------------------------------------------------
// Kernel 3: MFMA flash attention, software-pipelined (K-frag register dbuf +
// key-loop unroll x2, V hoisted, batched LDS phase, setprio) + pt LDS dbuf.
// GRID PACKING is the R3 fix: P=18 -> KP=512, grid 1296 = 512+512+272 at the
// 2-blocks/CU register bracket -> 3 balanced generations (R2's P=8 gave 576 =
// 512+64 -> 2 generations, the 2nd at 25% CU utilization).
// ---------------------------------------------------------------------------
__global__ __launch_bounds__(256, 2) void
k_attn(const ushort* __restrict__ tok, const ushort* __restrict__ tokT,
       float* __restrict__ pl, ushort* __restrict__ pacc, int P, int KP) {
    __shared__ ushort pt[2][4][64 * 40];   // double-buffered per-wave P^T, 40 KB

    const int QW = NPIX / 256;          // 36 query chunks per batch
    int bid = blockIdx.x;
    int qc = bid % QW; int rest = bid / QW;
    int p = rest % P;  int b = rest / P;
    int tid = threadIdx.x;
    int wv = tid >> 6, lane = tid & 63;
    int quad = lane >> 4, l15 = lane & 15;

    const ushort* tb  = tok  + (size_t)b * NPIX * NCH;
    const ushort* tbT = tokT + (size_t)b * NCH * NPIX;
    int qwave = qc * 256 + wv * 64;

    // Q fragments: B operand of S^T (lane n=l15, k=quad*8+j+32kc); scale folded.
    short8 qf[4][2];
    const float scale = 0.125f * 1.44269504088896340736f;  // 1/sqrt(C) * log2(e)
    #pragma unroll
    for (int n = 0; n < 4; ++n) {
        const ushort* qr = tb + (size_t)(qwave + 16 * n + l15) * NCH + quad * 8;
        #pragma unroll
        for (int kc = 0; kc < 2; ++kc) {
            ushort8 raw = *(const ushort8*)(qr + 32 * kc);
            short8 f;
            #pragma unroll
            for (int e = 0; e < 8; ++e) f[e] = (short)f2bf_rne(bf2f(raw[e]) * scale);
            qf[n][kc] = f;
        }
    }

    f32x4 O[4][4];                      // O^T acc: D[c=16m+quad*4+reg][q=16n+l15]
    #pragma unroll
    for (int m = 0; m < 4; ++m)
        #pragma unroll
        for (int n = 0; n < 4; ++n) O[m][n] = (f32x4){0.f, 0.f, 0.f, 0.f};
    float lrun[4] = {0.f, 0.f, 0.f, 0.f};

    int k0 = p * KP;
    ushort* ptw0 = &pt[0][wv][0];
    ushort* ptw1 = &pt[1][wv][0];

    short8 kfA[4], kfB[4];
    attn_loadK(tb, k0, l15, quad, kfA);
    for (int kb = 0; kb < KP; kb += 64) {
        attn_loadK(tb, k0 + kb + 32, l15, quad, kfB);        // prefetch body 2
        attn_body(tbT, k0 + kb, l15, quad, ptw0, qf, kfA, O, lrun);
        int nxt = (kb + 64 < KP) ? (k0 + kb + 64) : k0;      // last: dummy (valid) addr
        attn_loadK(tb, nxt, l15, quad, kfA);                 // prefetch next iter
        attn_body(tbT, k0 + kb + 32, l15, quad, ptw1, qf, kfB, O, lrun);
    }

    #pragma unroll
    for (int n = 0; n < 4; ++n) {       // disjoint key subsets per quad
        lrun[n] += __shfl_xor(lrun[n], 16, 64);
        lrun[n] += __shfl_xor(lrun[n], 32, 64);
    }
    size_t bp = (size_t)b * P + p;
    if (quad == 0) {
        #pragma unroll
        for (int n = 0; n < 4; ++n)
            pl[bp * NPIX + qwave + 16 * n + l15] = lrun[n];
    }
    // pacc[b][p][c][n]: per (n,m,r) scalar 2B stores; across l15 lanes each
    // (m,r) is a 32B contiguous segment -> sector-aligned.
    #pragma unroll
    for (int n = 0; n < 4; ++n) {
        int qg = qwave + 16 * n + l15;
        #pragma unroll
        for (int m = 0; m < 4; ++m) {
            #pragma unroll
            for (int r = 0; r < 4; ++r) {
                int c = 16 * m + quad * 4 + r;
                pacc[(bp * NCH + c) * NPIX + qg] = f2bf_rne(O[m][n][r]);
            }
        }
    }
}

// ---------------------------------------------------------------------------
// Kernel 3b: Linv[b][n] = 0.2 / sum_p pl[b][p][n]
// ---------------------------------------------------------------------------
__global__ void k_norm(const float* __restrict__ pl, float* __restrict__ linv, int P) {
    int idx = blockIdx.x * blockDim.x + threadIdx.x;
    if (idx >= TOTPIX) return;
    int b = idx / NPIX, n = idx % NPIX;
    float L = 0.f;
    for (int p = 0; p < P; ++p) L += pl[((size_t)b * P + p) * NPIX + n];
    linv[idx] = 0.2f / L;
}

// ---------------------------------------------------------------------------
// Kernel 4: fully-coalesced combine. thread = (b, c, 8-n segment):
// o[n] = sum_p pacc[b][p][c][n] (ushort8 rows), out = x + Linv[n]*o[n].
// ---------------------------------------------------------------------------
__global__ void k_combine(const float* __restrict__ x, const float* __restrict__ linv,
                          const ushort* __restrict__ pacc, float* __restrict__ out,
                          int P) {
    int gid = blockIdx.x * blockDim.x + threadIdx.x;   // (b*NCH + c)*1152 + seg
    if (gid >= BB * NCH * (NPIX / 8)) return;
    int seg = gid % (NPIX / 8);
    int bc  = gid / (NPIX / 8);
    int b = bc / NCH;
    int n0 = seg * 8;
    float o[8] = {0.f, 0.f, 0.f, 0.f, 0.f, 0.f, 0.f, 0.f};
    for (int p = 0; p < P; ++p) {
        ushort8 t = *(const ushort8*)(pacc +
            (((size_t)b * P + p) * NCH + (bc % NCH)) * NPIX + n0);
        #pragma unroll
        for (int e = 0; e < 8; ++e) o[e] += bf2f(t[e]);
    }
    const float* lv = linv + (size_t)b * NPIX + n0;
    const float* xb = x + (size_t)bc * NPIX + n0;
    float* ob = out + (size_t)bc * NPIX + n0;
    #pragma unroll
    for (int e = 0; e < 8; ++e)
        ob[e] = fmaf(lv[e], o[e], xb[e]);
}

// ---------------------------------------------------------------------------
extern "C" void kernel_launch(void* const* d_in, const int* in_sizes, int n_in,
                              void* d_out, int out_size, void* d_ws, size_t ws_size,
                              hipStream_t stream) {
    const float* x      = (const float*)d_in[0];
    const float* w_red  = (const float*)d_in[1];
    const float* b_red  = (const float*)d_in[2];
    const float* w_dil  = (const float*)d_in[3];
    const float* b_dil  = (const float*)d_in[4];
    const float* w_fuse = (const float*)d_in[5];
    const float* b_fuse = (const float*)d_in[6];
    float* out = (float*)d_out;

    // ws: xred f32 | FT bf16 | tok bf16 | tokT bf16 | pl f32 | linv f32 | pacc bf16
    const size_t XRED_N = (size_t)BB * INNER * NPIX;
    const size_t FT_N   = (size_t)64 * TOTPIX;
    const size_t TOK_N  = (size_t)BB * NPIX * NCH;
    const size_t HEAD_B = XRED_N * 4 + (FT_N + 2 * TOK_N) * 2 + TOTPIX * 4;
    int P = 0;
    // P=18: KP=512 (mult of 64 for the x2-unrolled key loop), grid 1296 ->
    // 3 balanced generations at 2-blocks/CU capacity (512 co-resident).
    // Fallbacks keep KP a multiple of 64.
    const int cands[6] = {18, 12, 8, 4, 2, 1};
    for (int ci = 0; ci < 6; ++ci) {
        int cp = cands[ci];
        size_t need = HEAD_B + (size_t)BB * cp * NPIX * (4 + NCH * 2);
        if (ws_size >= need) { P = cp; break; }
    }
    if (P == 0) return;

    float*  xred = (float*)d_ws;
    ushort* FT   = (ushort*)(xred + XRED_N);
    ushort* tok  = FT + FT_N;
    ushort* tokT = tok + TOK_N;
    float*  pl   = (float*)(tokT + TOK_N);
    float*  linv = pl + (size_t)BB * P * NPIX;
    ushort* pacc = (ushort*)(linv + TOTPIX);

    k_reduce <<<(TOTPIX + 255) / 256, 256, 0, stream>>>(x, w_red, b_red, xred);
    k_feat   <<<3 * TOTPIX / 256, 256, 0, stream>>>(xred, w_dil, b_dil, FT);
    k_fuse   <<<TOTPIX / 64, 256, 0, stream>>>(FT, w_fuse, b_fuse, tok, tokT);
    k_attn   <<<BB * P * (NPIX / 256), 256, 0, stream>>>(tok, tokT, pl, pacc,
                                                         P, NPIX / P);
    k_norm   <<<(TOTPIX + 255) / 256, 256, 0, stream>>>(pl, linv, P);
    k_combine<<<(BB * NCH * (NPIX / 8) + 255) / 256, 256, 0, stream>>>(x, linv, pacc,
                                                                       out, P);
}

// Round 4
// 192.114 us; speedup vs baseline: 1.0586x; 1.0586x over previous
//
#include <hip/hip_runtime.h>

#define HW    96
#define NPIX  9216        // 96*96
#define NCH   64          // C
#define INNER 3
#define NDIL  3
#define BB    2           // batch
#define TOTPIX (BB * NPIX)   // 18432
#define NT32  (NPIX / 32)    // 288 key tiles per batch

typedef __attribute__((ext_vector_type(8))) short short8;            // 8 bf16
typedef __attribute__((ext_vector_type(8))) unsigned short ushort8;  // 8 bf16 raw
typedef __attribute__((ext_vector_type(4))) float f32x4;

__device__ __forceinline__ ushort f2bf_rne(float f) {
    unsigned u = __float_as_uint(f);
    u += 0x7fffu + ((u >> 16) & 1u);
    return (ushort)(u >> 16);
}
__device__ __forceinline__ float bf2f(ushort u) {
    return __uint_as_float((unsigned)u << 16);
}
// pack hi16(a),hi16(b) -> dword {bf16(b)<<16 | bf16(a)} (trunc; ratio-safe for P)
__device__ __forceinline__ unsigned pack_bf(float lo, float hi) {
    return __builtin_amdgcn_perm(__float_as_uint(hi), __float_as_uint(lo), 0x07060302u);
}

// ---------------------------------------------------------------------------
// Kernel 1: x_red = 1x1 conv (64 -> 3 channels)
// ---------------------------------------------------------------------------
__global__ void k_reduce(const float* __restrict__ x, const float* __restrict__ w_red,
                         const float* __restrict__ b_red, float* __restrict__ xred) {
    int pix = blockIdx.x * blockDim.x + threadIdx.x;
    if (pix >= TOTPIX) return;
    int b = pix / NPIX, n = pix % NPIX;
    float a0 = b_red[0], a1 = b_red[1], a2 = b_red[2];
    const float* xb = x + (size_t)b * NCH * NPIX + n;
    #pragma unroll
    for (int c = 0; c < NCH; ++c) {
        float xv = xb[(size_t)c * NPIX];
        a0 = fmaf(w_red[0 * NCH + c], xv, a0);
        a1 = fmaf(w_red[1 * NCH + c], xv, a1);
        a2 = fmaf(w_red[2 * NCH + c], xv, a2);
    }
    float* xr = xred + (size_t)b * INNER * NPIX + n;
    xr[0 * NPIX] = a0; xr[1 * NPIX] = a1; xr[2 * NPIX] = a2;
}

// ---------------------------------------------------------------------------
// Kernel 2a: features. thread = (pixel, dilation i3). Writes FT[j][pix] bf16,
// j = i3*18 + t*3 + o. Rows 54..63 never written — zero-weighted in k_fuse.
// ---------------------------------------------------------------------------
__global__ __launch_bounds__(256) void
k_feat(const float* __restrict__ xred, const float* __restrict__ w_dil,
       const float* __restrict__ b_dil, ushort* __restrict__ FT) {
    int gid = blockIdx.x * 256 + threadIdx.x;      // 3 * 18432 threads
    int i3 = gid / TOTPIX;                          // wave-uniform
    int pix = gid - i3 * TOTPIX;
    int b = pix / NPIX, n = pix % NPIX;
    int h = n / HW, w = n % HW;
    const float* xr = xred + (size_t)b * INNER * NPIX;
    int d = i3 + 1;

    float co[3] = {b_dil[i3 * 3 + 0], b_dil[i3 * 3 + 1], b_dil[i3 * 3 + 2]};
    #pragma unroll
    for (int ci = 0; ci < 3; ++ci) {
        const float* xo = xr + ci * NPIX;
        #pragma unroll
        for (int kh = 0; kh < 3; ++kh) {
            int hh = h + (kh - 1) * d;
            #pragma unroll
            for (int kw = 0; kw < 3; ++kw) {
                int ww = w + (kw - 1) * d;
                float v = ((unsigned)hh < HW && (unsigned)ww < HW) ? xo[hh * HW + ww] : 0.f;
                #pragma unroll
                for (int o = 0; o < 3; ++o)
                    co[o] = fmaf(w_dil[(9 * i3 + 3 * o + ci) * 9 + kh * 3 + kw], v, co[o]);
            }
        }
    }

    float tf[6][3];
    #pragma unroll
    for (int o = 0; o < 3; ++o) {
        const float* xo = xr + o * NPIX;
        tf[0][o] = xo[h * HW + w];
        tf[1][o] = xo[h * HW + (HW - 1 - w)];
        tf[2][o] = xo[(HW - 1 - h) * HW + w];
        tf[3][o] = xo[w * HW + (HW - 1 - h)];
        tf[4][o] = xo[(HW - 1 - h) * HW + (HW - 1 - w)];
        tf[5][o] = xo[(HW - 1 - w) * HW + h];
    }

    #pragma unroll
    for (int t = 0; t < 6; ++t)
        #pragma unroll
        for (int o = 0; o < 3; ++o) {
            int j = i3 * 18 + t * 3 + o;
            FT[(size_t)j * TOTPIX + pix] = f2bf_rne(co[o] * tf[t][o]);
        }
}

// ---------------------------------------------------------------------------
// Kernel 2b: fuse conv as MFMA GEMM, 64 px/block (grid 288).
// tokT is now TILED: [b][n>>5][c][n&31] so k_attn's V staging is contiguous.
// ---------------------------------------------------------------------------
__global__ __launch_bounds__(256) void
k_fuse(const ushort* __restrict__ FT, const float* __restrict__ w_fuse,
       const float* __restrict__ b_fuse, ushort* __restrict__ tok,
       ushort* __restrict__ tokTt) {
    __shared__ ushort wpad[64 * 72];     // [c][j pad 72]
    __shared__ float  bsh[64];
    __shared__ ushort tile[64 * 72];     // [c][64 px + 8 pad]

    int tid = threadIdx.x;
    for (int i = tid; i < 64 * 64; i += 256) {
        int c = i >> 6, j = i & 63;
        wpad[c * 72 + j] = (j < 54) ? f2bf_rne(w_fuse[c * 54 + j]) : (ushort)0;
    }
    if (tid < 64) bsh[tid] = b_fuse[tid];
    __syncthreads();

    int wv = tid >> 6, lane = tid & 63, quad = lane >> 4, l15 = lane & 15;
    int px0 = blockIdx.x * 64;

    short8 af[4][2];
    #pragma unroll
    for (int m = 0; m < 4; ++m)
        #pragma unroll
        for (int kc = 0; kc < 2; ++kc)
            af[m][kc] = *(const short8*)&wpad[(16 * m + l15) * 72 + quad * 8 + 32 * kc];

    f32x4 acc[4];
    #pragma unroll
    for (int m = 0; m < 4; ++m) acc[m] = (f32x4){0.f, 0.f, 0.f, 0.f};

    int px = px0 + wv * 16 + l15;
    #pragma unroll
    for (int kc = 0; kc < 2; ++kc) {
        short8 bf;
        #pragma unroll
        for (int jj = 0; jj < 8; ++jj)
            bf[jj] = (short)FT[(size_t)(quad * 8 + jj + 32 * kc) * TOTPIX + px];
        #pragma unroll
        for (int m = 0; m < 4; ++m)
            acc[m] = __builtin_amdgcn_mfma_f32_16x16x32_bf16(af[m][kc], bf, acc[m], 0, 0, 0);
    }

    #pragma unroll
    for (int m = 0; m < 4; ++m)
        #pragma unroll
        for (int r = 0; r < 4; ++r) {
            int c = 16 * m + quad * 4 + r;
            tile[c * 72 + wv * 16 + l15] = f2bf_rne(acc[m][r] + bsh[c]);
        }
    __syncthreads();

    int b0 = px0 / NPIX, n0 = px0 % NPIX;
    {   // tok[b][n][c]
        int lp = tid >> 2, part = tid & 3;
        ushort row[16];
        #pragma unroll
        for (int k = 0; k < 16; ++k) row[k] = tile[(part * 16 + k) * 72 + lp];
        ushort* dst = tok + ((size_t)b0 * NPIX + n0 + lp) * NCH + part * 16;
        *(ushort8*)&dst[0] = *(const ushort8*)&row[0];
        *(ushort8*)&dst[8] = *(const ushort8*)&row[8];
    }
    {   // tokTt[b][n>>5][c][n&31] (32-key tiles)
        int c = tid >> 2, seg = tid & 3;
        int n = n0 + seg * 16;
        size_t base = (((size_t)b0 * NT32 + (n >> 5)) * 64 + c) * 32 + (n & 31);
        *(ushort8*)&tokTt[base]     = *(const ushort8*)&tile[c * 72 + seg * 16];
        *(ushort8*)&tokTt[base + 8] = *(const ushort8*)&tile[c * 72 + seg * 16 + 8];
    }
}

// ---------------------------------------------------------------------------
// Kernel 3: MFMA flash attention with COOPERATIVE LDS STAGING of K and V.
// R0-R3 evidence: wall invariant to partitioning/scheduling, all pipes <30%
// busy -> per-CU VMEM(TA) bound: each of the 4 waves per block was loading
// the IDENTICAL K/V fragments (4x redundant) with 16-row scattered instrs.
// Now: per 32-key tile, the block stages K (4KB, contiguous from tok) and V
// (4KB, contiguous from tiled tokTt) into padded LDS once — 4x fewer VMEM
// instructions, fully coalesced. Double-buffered, reg-staged (T14: global
// loads at body top, ds_writes after body, one barrier per body). 
// launch_bounds(256,3): pin the 3-blocks/CU bracket.
// ---------------------------------------------------------------------------
__global__ __launch_bounds__(256, 3) void
k_attn(const ushort* __restrict__ tok, const ushort* __restrict__ tokTt,
       float* __restrict__ pl, ushort* __restrict__ pacc, int P, int KP) {
    __shared__ ushort pt[4][64 * 40];      // per-wave P^T [q][32key + 8 pad], 20 KB
    __shared__ ushort ldsK[2][32 * 80];    // [key][64ch + 16 pad], 2 x 5 KB
    __shared__ ushort ldsV[2][64 * 40];    // [ch][32key + 8 pad], 2 x 5 KB

    const int QW = NPIX / 256;          // 36 query chunks per batch
    int bid = blockIdx.x;
    int qc = bid % QW; int rest = bid / QW;
    int p = rest % P;  int b = rest / P;
    int tid = threadIdx.x;
    int wv = tid >> 6, lane = tid & 63;
    int quad = lane >> 4, l15 = lane & 15;

    const ushort* tb  = tok + (size_t)b * NPIX * NCH;
    const ushort* tvb = tokTt + (size_t)b * NT32 * (64 * 32);
    int qwave = qc * 256 + wv * 64;

    // staging decomposition (per thread: one 16B chunk of each tile)
    int sk_off = (tid >> 3) * 80 + (tid & 7) * 8;   // [key=tid>>3][ch=(tid&7)*8]
    int sv_off = (tid >> 2) * 40 + (tid & 3) * 8;   // [ch=tid>>2][kk=(tid&3)*8]

    // Q fragments: B operand of S^T (lane n=l15, k=quad*8+j+32kc); scale folded.
    short8 qf[4][2];
    const float scale = 0.125f * 1.44269504088896340736f;  // 1/sqrt(C) * log2(e)
    #pragma unroll
    for (int n = 0; n < 4; ++n) {
        const ushort* qr = tb + (size_t)(qwave + 16 * n + l15) * NCH + quad * 8;
        #pragma unroll
        for (int kc = 0; kc < 2; ++kc) {
            ushort8 raw = *(const ushort8*)(qr + 32 * kc);
            short8 f;
            #pragma unroll
            for (int e = 0; e < 8; ++e) f[e] = (short)f2bf_rne(bf2f(raw[e]) * scale);
            qf[n][kc] = f;
        }
    }

    f32x4 O[4][4];                      // O^T acc: D[c=16m+quad*4+reg][q=16n+l15]
    #pragma unroll
    for (int m = 0; m < 4; ++m)
        #pragma unroll
        for (int n = 0; n < 4; ++n) O[m][n] = (f32x4){0.f, 0.f, 0.f, 0.f};
    float lrun[4] = {0.f, 0.f, 0.f, 0.f};

    const float FM = 16.0f;             // fixed exp2-domain shift
    int k0 = p * KP;
    ushort* ptw = &pt[wv][0];
    int nt = KP / 32;

    // prologue: stage tile 0
    {
        ushort8 gK = *(const ushort8*)(tb + (size_t)k0 * NCH + tid * 8);
        ushort8 gV = *(const ushort8*)(tvb + ((size_t)(k0 >> 5)) * 2048 + tid * 8);
        *(ushort8*)&ldsK[0][sk_off] = gK;
        *(ushort8*)&ldsV[0][sv_off] = gV;
    }
    __syncthreads();

    for (int t = 0; t < nt; ++t) {
        int cur = t & 1;
        int kbase = k0 + t * 32;
        bool pre = (t + 1 < nt);

        // issue next tile's global loads EARLY (T14: latency hides under body)
        ushort8 nK, nV;
        if (pre) {
            nK = *(const ushort8*)(tb + (size_t)(kbase + 32) * NCH + tid * 8);
            nV = *(const ushort8*)(tvb + ((size_t)((kbase + 32) >> 5)) * 2048 + tid * 8);
        }

        // fragments from LDS (shared by all 4 waves)
        short8 kd[4], vf[4];
        #pragma unroll
        for (int m2 = 0; m2 < 2; ++m2)
            #pragma unroll
            for (int kc = 0; kc < 2; ++kc)
                kd[2 * m2 + kc] = *(const short8*)&ldsK[cur][(16 * m2 + l15) * 80 +
                                                            quad * 8 + 32 * kc];
        #pragma unroll
        for (int mc = 0; mc < 4; ++mc)
            vf[mc] = *(const short8*)&ldsV[cur][(16 * mc + l15) * 40 + quad * 8];

        // S^T 32-key step: D[key][q]
        f32x4 S[2][4];
        #pragma unroll
        for (int m = 0; m < 2; ++m)
            #pragma unroll
            for (int n = 0; n < 4; ++n) S[m][n] = (f32x4){0.f, 0.f, 0.f, 0.f};

        __builtin_amdgcn_s_setprio(1);
        #pragma unroll
        for (int m2 = 0; m2 < 2; ++m2)
            #pragma unroll
            for (int cc = 0; cc < 2; ++cc)
                #pragma unroll
                for (int n = 0; n < 4; ++n)
                    S[m2][n] = __builtin_amdgcn_mfma_f32_16x16x32_bf16(kd[2 * m2 + cc],
                                                                       qf[n][cc], S[m2][n],
                                                                       0, 0, 0);
        __builtin_amdgcn_s_setprio(0);

        // softmax numerators, fixed base: p = exp2(s - FM). ALL writes batched.
        #pragma unroll
        for (int n = 0; n < 4; ++n) {
            int q = 16 * n + l15;
            #pragma unroll
            for (int m2 = 0; m2 < 2; ++m2) {
                float p0 = __builtin_amdgcn_exp2f(S[m2][n][0] - FM);
                float p1 = __builtin_amdgcn_exp2f(S[m2][n][1] - FM);
                float p2 = __builtin_amdgcn_exp2f(S[m2][n][2] - FM);
                float p3 = __builtin_amdgcn_exp2f(S[m2][n][3] - FM);
                lrun[n] += (p0 + p1) + (p2 + p3);
                uint2 wd = make_uint2(pack_bf(p0, p1), pack_bf(p2, p3));
                // key_local = 16*m2 + quad*4 + reg
                *(uint2*)&ptw[q * 40 + m2 * 16 + quad * 4] = wd;
            }
        }

        // O^T += V^T·P^T (K=32): batched reads + MFMAs (same-wave pt region)
        __builtin_amdgcn_s_setprio(1);
        #pragma unroll
        for (int n = 0; n < 4; ++n) {
            short8 bfr = *(const short8*)&ptw[(16 * n + l15) * 40 + quad * 8];
            #pragma unroll
            for (int mc = 0; mc < 4; ++mc)
                O[mc][n] = __builtin_amdgcn_mfma_f32_16x16x32_bf16(vf[mc], bfr,
                                                                   O[mc][n], 0, 0, 0);
        }
        __builtin_amdgcn_s_setprio(0);

        // write staged regs into the OTHER buffer, then one barrier per body
        if (pre) {
            *(ushort8*)&ldsK[cur ^ 1][sk_off] = nK;
            *(ushort8*)&ldsV[cur ^ 1][sv_off] = nV;
        }
        __syncthreads();
    }

    #pragma unroll
    for (int n = 0; n < 4; ++n) {       // disjoint key subsets per quad
        lrun[n] += __shfl_xor(lrun[n], 16, 64);
        lrun[n] += __shfl_xor(lrun[n], 32, 64);
    }
    size_t bp = (size_t)b * P + p;
    if (quad == 0) {
        #pragma unroll
        for (int n = 0; n < 4; ++n)
            pl[bp * NPIX + qwave + 16 * n + l15] = lrun[n];
    }
    // pacc[b][p][c][n]: per (n,m,r) scalar 2B stores; across l15 lanes each
    // (m,r) is a 32B contiguous segment -> sector-aligned.
    #pragma unroll
    for (int n = 0; n < 4; ++n) {
        int qg = qwave + 16 * n + l15;
        #pragma unroll
        for (int m = 0; m < 4; ++m) {
            #pragma unroll
            for (int r = 0; r < 4; ++r) {
                int c = 16 * m + quad * 4 + r;
                pacc[(bp * NCH + c) * NPIX + qg] = f2bf_rne(O[m][n][r]);
            }
        }
    }
}

// ---------------------------------------------------------------------------
// Kernel 3b: Linv[b][n] = 0.2 / sum_p pl[b][p][n]
// ---------------------------------------------------------------------------
__global__ void k_norm(const float* __restrict__ pl, float* __restrict__ linv, int P) {
    int idx = blockIdx.x * blockDim.x + threadIdx.x;
    if (idx >= TOTPIX) return;
    int b = idx / NPIX, n = idx % NPIX;
    float L = 0.f;
    for (int p = 0; p < P; ++p) L += pl[((size_t)b * P + p) * NPIX + n];
    linv[idx] = 0.2f / L;
}

// ---------------------------------------------------------------------------
// Kernel 4: fully-coalesced combine. thread = (b, c, 8-n segment):
// o[n] = sum_p pacc[b][p][c][n] (ushort8 rows), out = x + Linv[n]*o[n].
// ---------------------------------------------------------------------------
__global__ void k_combine(const float* __restrict__ x, const float* __restrict__ linv,
                          const ushort* __restrict__ pacc, float* __restrict__ out,
                          int P) {
    int gid = blockIdx.x * blockDim.x + threadIdx.x;   // (b*NCH + c)*1152 + seg
    if (gid >= BB * NCH * (NPIX / 8)) return;
    int seg = gid % (NPIX / 8);
    int bc  = gid / (NPIX / 8);
    int b = bc / NCH;
    int n0 = seg * 8;
    float o[8] = {0.f, 0.f, 0.f, 0.f, 0.f, 0.f, 0.f, 0.f};
    for (int p = 0; p < P; ++p) {
        ushort8 t = *(const ushort8*)(pacc +
            (((size_t)b * P + p) * NCH + (bc % NCH)) * NPIX + n0);
        #pragma unroll
        for (int e = 0; e < 8; ++e) o[e] += bf2f(t[e]);
    }
    const float* lv = linv + (size_t)b * NPIX + n0;
    const float* xb = x + (size_t)bc * NPIX + n0;
    float* ob = out + (size_t)bc * NPIX + n0;
    #pragma unroll
    for (int e = 0; e < 8; ++e)
        ob[e] = fmaf(lv[e], o[e], xb[e]);
}

// ---------------------------------------------------------------------------
extern "C" void kernel_launch(void* const* d_in, const int* in_sizes, int n_in,
                              void* d_out, int out_size, void* d_ws, size_t ws_size,
                              hipStream_t stream) {
    const float* x      = (const float*)d_in[0];
    const float* w_red  = (const float*)d_in[1];
    const float* b_red  = (const float*)d_in[2];
    const float* w_dil  = (const float*)d_in[3];
    const float* b_dil  = (const float*)d_in[4];
    const float* w_fuse = (const float*)d_in[5];
    const float* b_fuse = (const float*)d_in[6];
    float* out = (float*)d_out;

    // ws: xred f32 | FT bf16 | tok bf16 | tokTt bf16 | pl f32 | linv f32 | pacc bf16
    const size_t XRED_N = (size_t)BB * INNER * NPIX;
    const size_t FT_N   = (size_t)64 * TOTPIX;
    const size_t TOK_N  = (size_t)BB * NPIX * NCH;
    const size_t HEAD_B = XRED_N * 4 + (FT_N + 2 * TOK_N) * 2 + TOTPIX * 4;
    int P = 0;
    // KP = NPIX/P must be a multiple of 32 (tile size). P=18 -> KP=512.
    const int cands[6] = {18, 12, 8, 4, 2, 1};
    for (int ci = 0; ci < 6; ++ci) {
        int cp = cands[ci];
        size_t need = HEAD_B + (size_t)BB * cp * NPIX * (4 + NCH * 2);
        if (ws_size >= need) { P = cp; break; }
    }
    if (P == 0) return;

    float*  xred  = (float*)d_ws;
    ushort* FT    = (ushort*)(xred + XRED_N);
    ushort* tok   = FT + FT_N;
    ushort* tokTt = tok + TOK_N;
    float*  pl    = (float*)(tokTt + TOK_N);
    float*  linv  = pl + (size_t)BB * P * NPIX;
    ushort* pacc  = (ushort*)(linv + TOTPIX);

    k_reduce <<<(TOTPIX + 255) / 256, 256, 0, stream>>>(x, w_red, b_red, xred);
    k_feat   <<<3 * TOTPIX / 256, 256, 0, stream>>>(xred, w_dil, b_dil, FT);
    k_fuse   <<<TOTPIX / 64, 256, 0, stream>>>(FT, w_fuse, b_fuse, tok, tokTt);
    k_attn   <<<BB * P * (NPIX / 256), 256, 0, stream>>>(tok, tokTt, pl, pacc,
                                                         P, NPIX / P);
    k_norm   <<<(TOTPIX + 255) / 256, 256, 0, stream>>>(pl, linv, P);
    k_combine<<<(BB * NCH * (NPIX / 8) + 255) / 256, 256, 0, stream>>>(x, linv, pacc,
                                                                       out, P);
}

// Round 5
// 150.591 us; speedup vs baseline: 1.3505x; 1.2757x over previous
//
#include <hip/hip_runtime.h>

#define HW    96
#define NPIX  9216        // 96*96
#define NCH   64          // C
#define INNER 3
#define NDIL  3
#define BB    2           // batch
#define TOTPIX (BB * NPIX)   // 18432
#define NT32  (NPIX / 32)    // 288 key tiles per batch

typedef __attribute__((ext_vector_type(8))) short short8;            // 8 bf16
typedef __attribute__((ext_vector_type(8))) unsigned short ushort8;  // 8 bf16 raw
typedef __attribute__((ext_vector_type(4))) float f32x4;

__device__ __forceinline__ ushort f2bf_rne(float f) {
    unsigned u = __float_as_uint(f);
    u += 0x7fffu + ((u >> 16) & 1u);
    return (ushort)(u >> 16);
}
__device__ __forceinline__ float bf2f(ushort u) {
    return __uint_as_float((unsigned)u << 16);
}
// pack hi16(a),hi16(b) -> dword {bf16(b)<<16 | bf16(a)} (trunc; ratio-safe for P)
__device__ __forceinline__ unsigned pack_bf(float lo, float hi) {
    return __builtin_amdgcn_perm(__float_as_uint(hi), __float_as_uint(lo), 0x07060302u);
}

// ---------------------------------------------------------------------------
// Kernel 1: x_red = 1x1 conv (64 -> 3 channels)
// ---------------------------------------------------------------------------
__global__ void k_reduce(const float* __restrict__ x, const float* __restrict__ w_red,
                         const float* __restrict__ b_red, float* __restrict__ xred) {
    int pix = blockIdx.x * blockDim.x + threadIdx.x;
    if (pix >= TOTPIX) return;
    int b = pix / NPIX, n = pix % NPIX;
    float a0 = b_red[0], a1 = b_red[1], a2 = b_red[2];
    const float* xb = x + (size_t)b * NCH * NPIX + n;
    #pragma unroll
    for (int c = 0; c < NCH; ++c) {
        float xv = xb[(size_t)c * NPIX];
        a0 = fmaf(w_red[0 * NCH + c], xv, a0);
        a1 = fmaf(w_red[1 * NCH + c], xv, a1);
        a2 = fmaf(w_red[2 * NCH + c], xv, a2);
    }
    float* xr = xred + (size_t)b * INNER * NPIX + n;
    xr[0 * NPIX] = a0; xr[1 * NPIX] = a1; xr[2 * NPIX] = a2;
}

// ---------------------------------------------------------------------------
// Kernel 2a: features. thread = (pixel, dilation i3). Writes FT[j][pix] bf16,
// j = i3*18 + t*3 + o. Rows 54..63 never written — zero-weighted in k_fuse.
// ---------------------------------------------------------------------------
__global__ __launch_bounds__(256) void
k_feat(const float* __restrict__ xred, const float* __restrict__ w_dil,
       const float* __restrict__ b_dil, ushort* __restrict__ FT) {
    int gid = blockIdx.x * 256 + threadIdx.x;      // 3 * 18432 threads
    int i3 = gid / TOTPIX;                          // wave-uniform
    int pix = gid - i3 * TOTPIX;
    int b = pix / NPIX, n = pix % NPIX;
    int h = n / HW, w = n % HW;
    const float* xr = xred + (size_t)b * INNER * NPIX;
    int d = i3 + 1;

    float co[3] = {b_dil[i3 * 3 + 0], b_dil[i3 * 3 + 1], b_dil[i3 * 3 + 2]};
    #pragma unroll
    for (int ci = 0; ci < 3; ++ci) {
        const float* xo = xr + ci * NPIX;
        #pragma unroll
        for (int kh = 0; kh < 3; ++kh) {
            int hh = h + (kh - 1) * d;
            #pragma unroll
            for (int kw = 0; kw < 3; ++kw) {
                int ww = w + (kw - 1) * d;
                float v = ((unsigned)hh < HW && (unsigned)ww < HW) ? xo[hh * HW + ww] : 0.f;
                #pragma unroll
                for (int o = 0; o < 3; ++o)
                    co[o] = fmaf(w_dil[(9 * i3 + 3 * o + ci) * 9 + kh * 3 + kw], v, co[o]);
            }
        }
    }

    float tf[6][3];
    #pragma unroll
    for (int o = 0; o < 3; ++o) {
        const float* xo = xr + o * NPIX;
        tf[0][o] = xo[h * HW + w];
        tf[1][o] = xo[h * HW + (HW - 1 - w)];
        tf[2][o] = xo[(HW - 1 - h) * HW + w];
        tf[3][o] = xo[w * HW + (HW - 1 - h)];
        tf[4][o] = xo[(HW - 1 - h) * HW + (HW - 1 - w)];
        tf[5][o] = xo[(HW - 1 - w) * HW + h];
    }

    #pragma unroll
    for (int t = 0; t < 6; ++t)
        #pragma unroll
        for (int o = 0; o < 3; ++o) {
            int j = i3 * 18 + t * 3 + o;
            FT[(size_t)j * TOTPIX + pix] = f2bf_rne(co[o] * tf[t][o]);
        }
}

// ---------------------------------------------------------------------------
// Kernel 2b: fuse conv as MFMA GEMM, 64 px/block (grid 288).
// tokT is TILED: [b][n>>5][c][n&31] so k_attn's V staging is contiguous.
// ---------------------------------------------------------------------------
__global__ __launch_bounds__(256) void
k_fuse(const ushort* __restrict__ FT, const float* __restrict__ w_fuse,
       const float* __restrict__ b_fuse, ushort* __restrict__ tok,
       ushort* __restrict__ tokTt) {
    __shared__ ushort wpad[64 * 72];     // [c][j pad 72]
    __shared__ float  bsh[64];
    __shared__ ushort tile[64 * 72];     // [c][64 px + 8 pad]

    int tid = threadIdx.x;
    for (int i = tid; i < 64 * 64; i += 256) {
        int c = i >> 6, j = i & 63;
        wpad[c * 72 + j] = (j < 54) ? f2bf_rne(w_fuse[c * 54 + j]) : (ushort)0;
    }
    if (tid < 64) bsh[tid] = b_fuse[tid];
    __syncthreads();

    int wv = tid >> 6, lane = tid & 63, quad = lane >> 4, l15 = lane & 15;
    int px0 = blockIdx.x * 64;

    short8 af[4][2];
    #pragma unroll
    for (int m = 0; m < 4; ++m)
        #pragma unroll
        for (int kc = 0; kc < 2; ++kc)
            af[m][kc] = *(const short8*)&wpad[(16 * m + l15) * 72 + quad * 8 + 32 * kc];

    f32x4 acc[4];
    #pragma unroll
    for (int m = 0; m < 4; ++m) acc[m] = (f32x4){0.f, 0.f, 0.f, 0.f};

    int px = px0 + wv * 16 + l15;
    #pragma unroll
    for (int kc = 0; kc < 2; ++kc) {
        short8 bf;
        #pragma unroll
        for (int jj = 0; jj < 8; ++jj)
            bf[jj] = (short)FT[(size_t)(quad * 8 + jj + 32 * kc) * TOTPIX + px];
        #pragma unroll
        for (int m = 0; m < 4; ++m)
            acc[m] = __builtin_amdgcn_mfma_f32_16x16x32_bf16(af[m][kc], bf, acc[m], 0, 0, 0);
    }

    #pragma unroll
    for (int m = 0; m < 4; ++m)
        #pragma unroll
        for (int r = 0; r < 4; ++r) {
            int c = 16 * m + quad * 4 + r;
            tile[c * 72 + wv * 16 + l15] = f2bf_rne(acc[m][r] + bsh[c]);
        }
    __syncthreads();

    int b0 = px0 / NPIX, n0 = px0 % NPIX;
    {   // tok[b][n][c]
        int lp = tid >> 2, part = tid & 3;
        ushort row[16];
        #pragma unroll
        for (int k = 0; k < 16; ++k) row[k] = tile[(part * 16 + k) * 72 + lp];
        ushort* dst = tok + ((size_t)b0 * NPIX + n0 + lp) * NCH + part * 16;
        *(ushort8*)&dst[0] = *(const ushort8*)&row[0];
        *(ushort8*)&dst[8] = *(const ushort8*)&row[8];
    }
    {   // tokTt[b][n>>5][c][n&31] (32-key tiles)
        int c = tid >> 2, seg = tid & 3;
        int n = n0 + seg * 16;
        size_t base = (((size_t)b0 * NT32 + (n >> 5)) * 64 + c) * 32 + (n & 31);
        *(ushort8*)&tokTt[base]     = *(const ushort8*)&tile[c * 72 + seg * 16];
        *(ushort8*)&tokTt[base + 8] = *(const ushort8*)&tile[c * 72 + seg * 16 + 8];
    }
}

// ---------------------------------------------------------------------------
// Kernel 3: MFMA flash attention, OCCUPANCY-RESTRUCTURED.
// R0-R4 evidence: wall ~3000 cy per wave-body vs ~700 cy of issue work, all
// pipes <30% busy, occupancy pinned at 2 waves/SIMD by ~180 unified regs
// (84 arch + 64 O-acc + 32 S-acc). Fix: 32 q/wave (half the tile) ->
// O[4][2]+S[2][2] = 48 acc regs, ~115 total, launch_bounds(256,4) pins
// 4 waves/SIMD (50% occupancy). Block = 128 q. K/V LDS staging kept from R4
// (padded, double-buffered, reg-staged); stage-write moved mid-body so the
// staging regs die before vf loads.
// ---------------------------------------------------------------------------
__global__ __launch_bounds__(256, 4) void
k_attn(const ushort* __restrict__ tok, const ushort* __restrict__ tokTt,
       float* __restrict__ pl, ushort* __restrict__ pacc, int P, int KP) {
    __shared__ ushort pt[4][32 * 40];      // per-wave P^T [32 q][32key + 8 pad], 10 KB
    __shared__ ushort ldsK[2][32 * 80];    // [key][64ch + 16 pad], 2 x 5 KB
    __shared__ ushort ldsV[2][64 * 40];    // [ch][32key + 8 pad], 2 x 5 KB

    const int QW = NPIX / 128;          // 72 query chunks per batch
    int bid = blockIdx.x;
    int qc = bid % QW; int rest = bid / QW;
    int p = rest % P;  int b = rest / P;
    int tid = threadIdx.x;
    int wv = tid >> 6, lane = tid & 63;
    int quad = lane >> 4, l15 = lane & 15;

    const ushort* tb  = tok + (size_t)b * NPIX * NCH;
    const ushort* tvb = tokTt + (size_t)b * NT32 * (64 * 32);
    int qwave = qc * 128 + wv * 32;

    // staging decomposition (per thread: one 16B chunk of each tile)
    int sk_off = (tid >> 3) * 80 + (tid & 7) * 8;   // [key=tid>>3][ch=(tid&7)*8]
    int sv_off = (tid >> 2) * 40 + (tid & 3) * 8;   // [ch=tid>>2][kk=(tid&3)*8]

    // Q fragments: B operand of S^T (lane q=16n+l15, k=quad*8+j+32kc); scale folded.
    short8 qf[2][2];
    const float scale = 0.125f * 1.44269504088896340736f;  // 1/sqrt(C) * log2(e)
    #pragma unroll
    for (int n = 0; n < 2; ++n) {
        const ushort* qr = tb + (size_t)(qwave + 16 * n + l15) * NCH + quad * 8;
        #pragma unroll
        for (int kc = 0; kc < 2; ++kc) {
            ushort8 raw = *(const ushort8*)(qr + 32 * kc);
            short8 f;
            #pragma unroll
            for (int e = 0; e < 8; ++e) f[e] = (short)f2bf_rne(bf2f(raw[e]) * scale);
            qf[n][kc] = f;
        }
    }

    f32x4 O[4][2];                      // O^T acc: D[c=16m+quad*4+reg][q=16n+l15]
    #pragma unroll
    for (int m = 0; m < 4; ++m)
        #pragma unroll
        for (int n = 0; n < 2; ++n) O[m][n] = (f32x4){0.f, 0.f, 0.f, 0.f};
    float lrun[2] = {0.f, 0.f};

    const float FM = 16.0f;             // fixed exp2-domain shift
    int k0 = p * KP;
    ushort* ptw = &pt[wv][0];
    int nt = KP / 32;

    // prologue: stage tile 0
    {
        ushort8 gK = *(const ushort8*)(tb + (size_t)k0 * NCH + tid * 8);
        ushort8 gV = *(const ushort8*)(tvb + ((size_t)(k0 >> 5)) * 2048 + tid * 8);
        *(ushort8*)&ldsK[0][sk_off] = gK;
        *(ushort8*)&ldsV[0][sv_off] = gV;
    }
    __syncthreads();

    for (int t = 0; t < nt; ++t) {
        int cur = t & 1;
        int kbase = k0 + t * 32;
        bool pre = (t + 1 < nt);

        // issue next tile's global loads EARLY (latency hides under S phase)
        ushort8 nK, nV;
        if (pre) {
            nK = *(const ushort8*)(tb + (size_t)(kbase + 32) * NCH + tid * 8);
            nV = *(const ushort8*)(tvb + ((size_t)((kbase + 32) >> 5)) * 2048 + tid * 8);
        }

        // K fragments from LDS (shared by all 4 waves)
        short8 kd[4];
        #pragma unroll
        for (int m2 = 0; m2 < 2; ++m2)
            #pragma unroll
            for (int kc = 0; kc < 2; ++kc)
                kd[2 * m2 + kc] = *(const short8*)&ldsK[cur][(16 * m2 + l15) * 80 +
                                                            quad * 8 + 32 * kc];

        // S^T 32-key step: D[key][q]
        f32x4 S[2][2];
        #pragma unroll
        for (int m = 0; m < 2; ++m)
            #pragma unroll
            for (int n = 0; n < 2; ++n) S[m][n] = (f32x4){0.f, 0.f, 0.f, 0.f};

        __builtin_amdgcn_s_setprio(1);
        #pragma unroll
        for (int m2 = 0; m2 < 2; ++m2)
            #pragma unroll
            for (int cc = 0; cc < 2; ++cc)
                #pragma unroll
                for (int n = 0; n < 2; ++n)
                    S[m2][n] = __builtin_amdgcn_mfma_f32_16x16x32_bf16(kd[2 * m2 + cc],
                                                                       qf[n][cc], S[m2][n],
                                                                       0, 0, 0);
        __builtin_amdgcn_s_setprio(0);

        // mid-body: retire staging regs into the OTHER buffer (other waves
        // won't read it until after this body's end barrier)
        if (pre) {
            *(ushort8*)&ldsK[cur ^ 1][sk_off] = nK;
            *(ushort8*)&ldsV[cur ^ 1][sv_off] = nV;
        }

        // V^T fragments (A[ch][key]) from LDS
        short8 vf[4];
        #pragma unroll
        for (int mc = 0; mc < 4; ++mc)
            vf[mc] = *(const short8*)&ldsV[cur][(16 * mc + l15) * 40 + quad * 8];

        // softmax numerators, fixed base: p = exp2(s - FM). Writes batched.
        #pragma unroll
        for (int n = 0; n < 2; ++n) {
            int q = 16 * n + l15;
            #pragma unroll
            for (int m2 = 0; m2 < 2; ++m2) {
                float p0 = __builtin_amdgcn_exp2f(S[m2][n][0] - FM);
                float p1 = __builtin_amdgcn_exp2f(S[m2][n][1] - FM);
                float p2 = __builtin_amdgcn_exp2f(S[m2][n][2] - FM);
                float p3 = __builtin_amdgcn_exp2f(S[m2][n][3] - FM);
                lrun[n] += (p0 + p1) + (p2 + p3);
                uint2 wd = make_uint2(pack_bf(p0, p1), pack_bf(p2, p3));
                // key_local = 16*m2 + quad*4 + reg
                *(uint2*)&ptw[q * 40 + m2 * 16 + quad * 4] = wd;
            }
        }

        // O^T += V^T·P^T (K=32): batched reads + MFMAs (same-wave pt region)
        __builtin_amdgcn_s_setprio(1);
        #pragma unroll
        for (int n = 0; n < 2; ++n) {
            short8 bfr = *(const short8*)&ptw[(16 * n + l15) * 40 + quad * 8];
            #pragma unroll
            for (int mc = 0; mc < 4; ++mc)
                O[mc][n] = __builtin_amdgcn_mfma_f32_16x16x32_bf16(vf[mc], bfr,
                                                                   O[mc][n], 0, 0, 0);
        }
        __builtin_amdgcn_s_setprio(0);

        __syncthreads();
    }

    #pragma unroll
    for (int n = 0; n < 2; ++n) {       // disjoint key subsets per quad
        lrun[n] += __shfl_xor(lrun[n], 16, 64);
        lrun[n] += __shfl_xor(lrun[n], 32, 64);
    }
    size_t bp = (size_t)b * P + p;
    if (quad == 0) {
        #pragma unroll
        for (int n = 0; n < 2; ++n)
            pl[bp * NPIX + qwave + 16 * n + l15] = lrun[n];
    }
    // pacc[b][p][c][n]: per (n,m,r) scalar 2B stores; across l15 lanes each
    // (m,r) is a 32B contiguous segment -> sector-aligned.
    #pragma unroll
    for (int n = 0; n < 2; ++n) {
        int qg = qwave + 16 * n + l15;
        #pragma unroll
        for (int m = 0; m < 4; ++m) {
            #pragma unroll
            for (int r = 0; r < 4; ++r) {
                int c = 16 * m + quad * 4 + r;
                pacc[(bp * NCH + c) * NPIX + qg] = f2bf_rne(O[m][n][r]);
            }
        }
    }
}

// ---------------------------------------------------------------------------
// Kernel 3b: Linv[b][n] = 0.2 / sum_p pl[b][p][n]
// ---------------------------------------------------------------------------
__global__ void k_norm(const float* __restrict__ pl, float* __restrict__ linv, int P) {
    int idx = blockIdx.x * blockDim.x + threadIdx.x;
    if (idx >= TOTPIX) return;
    int b = idx / NPIX, n = idx % NPIX;
    float L = 0.f;
    for (int p = 0; p < P; ++p) L += pl[((size_t)b * P + p) * NPIX + n];
    linv[idx] = 0.2f / L;
}

// ---------------------------------------------------------------------------
// Kernel 4: fully-coalesced combine. thread = (b, c, 8-n segment):
// o[n] = sum_p pacc[b][p][c][n] (ushort8 rows), out = x + Linv[n]*o[n].
// ---------------------------------------------------------------------------
__global__ void k_combine(const float* __restrict__ x, const float* __restrict__ linv,
                          const ushort* __restrict__ pacc, float* __restrict__ out,
                          int P) {
    int gid = blockIdx.x * blockDim.x + threadIdx.x;   // (b*NCH + c)*1152 + seg
    if (gid >= BB * NCH * (NPIX / 8)) return;
    int seg = gid % (NPIX / 8);
    int bc  = gid / (NPIX / 8);
    int b = bc / NCH;
    int n0 = seg * 8;
    float o[8] = {0.f, 0.f, 0.f, 0.f, 0.f, 0.f, 0.f, 0.f};
    for (int p = 0; p < P; ++p) {
        ushort8 t = *(const ushort8*)(pacc +
            (((size_t)b * P + p) * NCH + (bc % NCH)) * NPIX + n0);
        #pragma unroll
        for (int e = 0; e < 8; ++e) o[e] += bf2f(t[e]);
    }
    const float* lv = linv + (size_t)b * NPIX + n0;
    const float* xb = x + (size_t)bc * NPIX + n0;
    float* ob = out + (size_t)bc * NPIX + n0;
    #pragma unroll
    for (int e = 0; e < 8; ++e)
        ob[e] = fmaf(lv[e], o[e], xb[e]);
}

// ---------------------------------------------------------------------------
extern "C" void kernel_launch(void* const* d_in, const int* in_sizes, int n_in,
                              void* d_out, int out_size, void* d_ws, size_t ws_size,
                              hipStream_t stream) {
    const float* x      = (const float*)d_in[0];
    const float* w_red  = (const float*)d_in[1];
    const float* b_red  = (const float*)d_in[2];
    const float* w_dil  = (const float*)d_in[3];
    const float* b_dil  = (const float*)d_in[4];
    const float* w_fuse = (const float*)d_in[5];
    const float* b_fuse = (const float*)d_in[6];
    float* out = (float*)d_out;

    // ws: xred f32 | FT bf16 | tok bf16 | tokTt bf16 | pl f32 | linv f32 | pacc bf16
    const size_t XRED_N = (size_t)BB * INNER * NPIX;
    const size_t FT_N   = (size_t)64 * TOTPIX;
    const size_t TOK_N  = (size_t)BB * NPIX * NCH;
    const size_t HEAD_B = XRED_N * 4 + (FT_N + 2 * TOK_N) * 2 + TOTPIX * 4;
    int P = 0;
    // KP = NPIX/P must be a multiple of 32 (tile size). P=16 -> KP=576.
    const int cands[5] = {16, 8, 4, 2, 1};
    for (int ci = 0; ci < 5; ++ci) {
        int cp = cands[ci];
        size_t need = HEAD_B + (size_t)BB * cp * NPIX * (4 + NCH * 2);
        if (ws_size >= need) { P = cp; break; }
    }
    if (P == 0) return;

    float*  xred  = (float*)d_ws;
    ushort* FT    = (ushort*)(xred + XRED_N);
    ushort* tok   = FT + FT_N;
    ushort* tokTt = tok + TOK_N;
    float*  pl    = (float*)(tokTt + TOK_N);
    float*  linv  = pl + (size_t)BB * P * NPIX;
    ushort* pacc  = (ushort*)(linv + TOTPIX);

    k_reduce <<<(TOTPIX + 255) / 256, 256, 0, stream>>>(x, w_red, b_red, xred);
    k_feat   <<<3 * TOTPIX / 256, 256, 0, stream>>>(xred, w_dil, b_dil, FT);
    k_fuse   <<<TOTPIX / 64, 256, 0, stream>>>(FT, w_fuse, b_fuse, tok, tokTt);
    k_attn   <<<BB * P * (NPIX / 128), 256, 0, stream>>>(tok, tokTt, pl, pacc,
                                                         P, NPIX / P);
    k_norm   <<<(TOTPIX + 255) / 256, 256, 0, stream>>>(pl, linv, P);
    k_combine<<<(BB * NCH * (NPIX / 8) + 255) / 256, 256, 0, stream>>>(x, linv, pacc,
                                                                       out, P);
}

// Round 6
// 149.106 us; speedup vs baseline: 1.3639x; 1.0100x over previous
//
#include <hip/hip_runtime.h>

#define HW    96
#define NPIX  9216        // 96*96
#define NCH   64          // C
#define INNER 3
#define NDIL  3
#define BB    2           // batch
#define TOTPIX (BB * NPIX)   // 18432
#define NT32  (NPIX / 32)    // 288 key tiles per batch

typedef __attribute__((ext_vector_type(8))) short short8;            // 8 bf16
typedef __attribute__((ext_vector_type(8))) unsigned short ushort8;  // 8 bf16 raw
typedef __attribute__((ext_vector_type(4))) float f32x4;
typedef __attribute__((ext_vector_type(4))) unsigned int uint32x4;

__device__ __forceinline__ ushort f2bf_rne(float f) {
    unsigned u = __float_as_uint(f);
    u += 0x7fffu + ((u >> 16) & 1u);
    return (ushort)(u >> 16);
}
__device__ __forceinline__ float bf2f(ushort u) {
    return __uint_as_float((unsigned)u << 16);
}
// pack hi16(a),hi16(b) -> dword {bf16(b)<<16 | bf16(a)} (trunc; ratio-safe for P)
__device__ __forceinline__ unsigned pack_bf(float lo, float hi) {
    return __builtin_amdgcn_perm(__float_as_uint(hi), __float_as_uint(lo), 0x07060302u);
}

// ---------------------------------------------------------------------------
// Kernel 1: x_red = 1x1 conv (64 -> 3 channels)
// ---------------------------------------------------------------------------
__global__ void k_reduce(const float* __restrict__ x, const float* __restrict__ w_red,
                         const float* __restrict__ b_red, float* __restrict__ xred) {
    int pix = blockIdx.x * blockDim.x + threadIdx.x;
    if (pix >= TOTPIX) return;
    int b = pix / NPIX, n = pix % NPIX;
    float a0 = b_red[0], a1 = b_red[1], a2 = b_red[2];
    const float* xb = x + (size_t)b * NCH * NPIX + n;
    #pragma unroll
    for (int c = 0; c < NCH; ++c) {
        float xv = xb[(size_t)c * NPIX];
        a0 = fmaf(w_red[0 * NCH + c], xv, a0);
        a1 = fmaf(w_red[1 * NCH + c], xv, a1);
        a2 = fmaf(w_red[2 * NCH + c], xv, a2);
    }
    float* xr = xred + (size_t)b * INNER * NPIX + n;
    xr[0 * NPIX] = a0; xr[1 * NPIX] = a1; xr[2 * NPIX] = a2;
}

// ---------------------------------------------------------------------------
// Kernel 2a: features. thread = (pixel, dilation i3). Writes FT[j][pix] bf16,
// j = i3*18 + t*3 + o. Rows 54..63 never written — zero-weighted in k_fuse.
// ---------------------------------------------------------------------------
__global__ __launch_bounds__(256) void
k_feat(const float* __restrict__ xred, const float* __restrict__ w_dil,
       const float* __restrict__ b_dil, ushort* __restrict__ FT) {
    int gid = blockIdx.x * 256 + threadIdx.x;      // 3 * 18432 threads
    int i3 = gid / TOTPIX;                          // wave-uniform
    int pix = gid - i3 * TOTPIX;
    int b = pix / NPIX, n = pix % NPIX;
    int h = n / HW, w = n % HW;
    const float* xr = xred + (size_t)b * INNER * NPIX;
    int d = i3 + 1;

    float co[3] = {b_dil[i3 * 3 + 0], b_dil[i3 * 3 + 1], b_dil[i3 * 3 + 2]};
    #pragma unroll
    for (int ci = 0; ci < 3; ++ci) {
        const float* xo = xr + ci * NPIX;
        #pragma unroll
        for (int kh = 0; kh < 3; ++kh) {
            int hh = h + (kh - 1) * d;
            #pragma unroll
            for (int kw = 0; kw < 3; ++kw) {
                int ww = w + (kw - 1) * d;
                float v = ((unsigned)hh < HW && (unsigned)ww < HW) ? xo[hh * HW + ww] : 0.f;
                #pragma unroll
                for (int o = 0; o < 3; ++o)
                    co[o] = fmaf(w_dil[(9 * i3 + 3 * o + ci) * 9 + kh * 3 + kw], v, co[o]);
            }
        }
    }

    float tf[6][3];
    #pragma unroll
    for (int o = 0; o < 3; ++o) {
        const float* xo = xr + o * NPIX;
        tf[0][o] = xo[h * HW + w];
        tf[1][o] = xo[h * HW + (HW - 1 - w)];
        tf[2][o] = xo[(HW - 1 - h) * HW + w];
        tf[3][o] = xo[w * HW + (HW - 1 - h)];
        tf[4][o] = xo[(HW - 1 - h) * HW + (HW - 1 - w)];
        tf[5][o] = xo[(HW - 1 - w) * HW + h];
    }

    #pragma unroll
    for (int t = 0; t < 6; ++t)
        #pragma unroll
        for (int o = 0; o < 3; ++o) {
            int j = i3 * 18 + t * 3 + o;
            FT[(size_t)j * TOTPIX + pix] = f2bf_rne(co[o] * tf[t][o]);
        }
}

// ---------------------------------------------------------------------------
// Kernel 2b: fuse conv as MFMA GEMM, 64 px/block (grid 288).
// tokT is TILED: [b][n>>5][c][n&31] so k_attn's V staging is contiguous.
// ---------------------------------------------------------------------------
__global__ __launch_bounds__(256) void
k_fuse(const ushort* __restrict__ FT, const float* __restrict__ w_fuse,
       const float* __restrict__ b_fuse, ushort* __restrict__ tok,
       ushort* __restrict__ tokTt) {
    __shared__ ushort wpad[64 * 72];     // [c][j pad 72]
    __shared__ float  bsh[64];
    __shared__ ushort tile[64 * 72];     // [c][64 px + 8 pad]

    int tid = threadIdx.x;
    for (int i = tid; i < 64 * 64; i += 256) {
        int c = i >> 6, j = i & 63;
        wpad[c * 72 + j] = (j < 54) ? f2bf_rne(w_fuse[c * 54 + j]) : (ushort)0;
    }
    if (tid < 64) bsh[tid] = b_fuse[tid];
    __syncthreads();

    int wv = tid >> 6, lane = tid & 63, quad = lane >> 4, l15 = lane & 15;
    int px0 = blockIdx.x * 64;

    short8 af[4][2];
    #pragma unroll
    for (int m = 0; m < 4; ++m)
        #pragma unroll
        for (int kc = 0; kc < 2; ++kc)
            af[m][kc] = *(const short8*)&wpad[(16 * m + l15) * 72 + quad * 8 + 32 * kc];

    f32x4 acc[4];
    #pragma unroll
    for (int m = 0; m < 4; ++m) acc[m] = (f32x4){0.f, 0.f, 0.f, 0.f};

    int px = px0 + wv * 16 + l15;
    #pragma unroll
    for (int kc = 0; kc < 2; ++kc) {
        short8 bf;
        #pragma unroll
        for (int jj = 0; jj < 8; ++jj)
            bf[jj] = (short)FT[(size_t)(quad * 8 + jj + 32 * kc) * TOTPIX + px];
        #pragma unroll
        for (int m = 0; m < 4; ++m)
            acc[m] = __builtin_amdgcn_mfma_f32_16x16x32_bf16(af[m][kc], bf, acc[m], 0, 0, 0);
    }

    #pragma unroll
    for (int m = 0; m < 4; ++m)
        #pragma unroll
        for (int r = 0; r < 4; ++r) {
            int c = 16 * m + quad * 4 + r;
            tile[c * 72 + wv * 16 + l15] = f2bf_rne(acc[m][r] + bsh[c]);
        }
    __syncthreads();

    int b0 = px0 / NPIX, n0 = px0 % NPIX;
    {   // tok[b][n][c]
        int lp = tid >> 2, part = tid & 3;
        ushort row[16];
        #pragma unroll
        for (int k = 0; k < 16; ++k) row[k] = tile[(part * 16 + k) * 72 + lp];
        ushort* dst = tok + ((size_t)b0 * NPIX + n0 + lp) * NCH + part * 16;
        *(ushort8*)&dst[0] = *(const ushort8*)&row[0];
        *(ushort8*)&dst[8] = *(const ushort8*)&row[8];
    }
    {   // tokTt[b][n>>5][c][n&31] (32-key tiles)
        int c = tid >> 2, seg = tid & 3;
        int n = n0 + seg * 16;
        size_t base = (((size_t)b0 * NT32 + (n >> 5)) * 64 + c) * 32 + (n & 31);
        *(ushort8*)&tokTt[base]     = *(const ushort8*)&tile[c * 72 + seg * 16];
        *(ushort8*)&tokTt[base + 8] = *(const ushort8*)&tile[c * 72 + seg * 16 + 8];
    }
}

// ---------------------------------------------------------------------------
// Kernel 3: MFMA flash attention, IN-REGISTER P (no pt LDS round-trip).
// Key insight: S^T output of lane (quad,l15) holds P for ITS OWN quad's key
// block; under the key re-ordering pos = 8*quad + 4*m2 + reg (m2<->quad field
// swap), the packed S fragment IS the PV B-operand fragment. Softmax packs
// exp2 results into 4 dwords per n and feeds O-MFMA directly from registers.
// The permutation is folded into the V staging LDS offsets (V stored at
// permuted key-positions): ldsV[ch][p] = V[ch][16*((p>>2)&1)+4*(p>>3)+(p&3)].
// K staging, lrun quad-disjoint reduction, epilogue unchanged.
// Also: ldsK padded to 72 ushorts/row (144 B = odd # of 16B chunks) ->
// conflict-free ds_read_b128.
// ---------------------------------------------------------------------------
__global__ __launch_bounds__(256, 4) void
k_attn(const ushort* __restrict__ tok, const ushort* __restrict__ tokTt,
       float* __restrict__ pl, ushort* __restrict__ pacc, int P, int KP) {
    __shared__ ushort ldsK[2][32 * 72];    // [key][64ch + 8 pad], 2 x 4.5 KB
    __shared__ ushort ldsV[2][64 * 40];    // [ch][32pos + 8 pad], 2 x 5 KB

    const int QW = NPIX / 128;          // 72 query chunks per batch
    int bid = blockIdx.x;
    int qc = bid % QW; int rest = bid / QW;
    int p = rest % P;  int b = rest / P;
    int tid = threadIdx.x;
    int wv = tid >> 6, lane = tid & 63;
    int quad = lane >> 4, l15 = lane & 15;

    const ushort* tb  = tok + (size_t)b * NPIX * NCH;
    const ushort* tvb = tokTt + (size_t)b * NT32 * (64 * 32);
    int qwave = qc * 128 + wv * 32;

    // staging decomposition (per thread: one 16B chunk of each tile)
    int sk_off = (tid >> 3) * 72 + (tid & 7) * 8;   // [key=tid>>3][ch=(tid&7)*8]
    // V: thread stages ch=tid>>2, keys kk=(tid&3)*8+e. Permuted destination:
    // e=0..3 -> pos base0+e, e=4..7 -> pos base1+(e&3)  (bijective, verified)
    int svj = tid & 3;
    int sv_b0 = (tid >> 2) * 40 + 8 * ((2 * svj) & 3) + 4 * (svj >> 1);
    int sv_b1 = (tid >> 2) * 40 + 8 * ((2 * svj + 1) & 3) + 4 * (svj >> 1);

    // Q fragments: B operand of S^T (lane q=16n+l15, k=quad*8+j+32kc); scale folded.
    short8 qf[2][2];
    const float scale = 0.125f * 1.44269504088896340736f;  // 1/sqrt(C) * log2(e)
    #pragma unroll
    for (int n = 0; n < 2; ++n) {
        const ushort* qr = tb + (size_t)(qwave + 16 * n + l15) * NCH + quad * 8;
        #pragma unroll
        for (int kc = 0; kc < 2; ++kc) {
            ushort8 raw = *(const ushort8*)(qr + 32 * kc);
            short8 f;
            #pragma unroll
            for (int e = 0; e < 8; ++e) f[e] = (short)f2bf_rne(bf2f(raw[e]) * scale);
            qf[n][kc] = f;
        }
    }

    f32x4 O[4][2];                      // O^T acc: D[c=16m+quad*4+reg][q=16n+l15]
    #pragma unroll
    for (int m = 0; m < 4; ++m)
        #pragma unroll
        for (int n = 0; n < 2; ++n) O[m][n] = (f32x4){0.f, 0.f, 0.f, 0.f};
    float lrun[2] = {0.f, 0.f};

    const float FM = 16.0f;             // fixed exp2-domain shift
    int k0 = p * KP;
    int nt = KP / 32;

    // prologue: stage tile 0
    {
        ushort8 gK = *(const ushort8*)(tb + (size_t)k0 * NCH + tid * 8);
        ushort8 gV = *(const ushort8*)(tvb + ((size_t)(k0 >> 5)) * 2048 + tid * 8);
        *(ushort8*)&ldsK[0][sk_off] = gK;
        uint32x4 v4 = *(uint32x4*)&gV;
        *(uint2*)&ldsV[0][sv_b0] = make_uint2(v4.x, v4.y);
        *(uint2*)&ldsV[0][sv_b1] = make_uint2(v4.z, v4.w);
    }
    __syncthreads();

    for (int t = 0; t < nt; ++t) {
        int cur = t & 1;
        int kbase = k0 + t * 32;
        bool pre = (t + 1 < nt);

        // issue next tile's global loads EARLY (latency hides under S phase)
        ushort8 nK, nV;
        if (pre) {
            nK = *(const ushort8*)(tb + (size_t)(kbase + 32) * NCH + tid * 8);
            nV = *(const ushort8*)(tvb + ((size_t)((kbase + 32) >> 5)) * 2048 + tid * 8);
        }

        // K fragments from LDS (shared by all 4 waves)
        short8 kd[4];
        #pragma unroll
        for (int m2 = 0; m2 < 2; ++m2)
            #pragma unroll
            for (int kc = 0; kc < 2; ++kc)
                kd[2 * m2 + kc] = *(const short8*)&ldsK[cur][(16 * m2 + l15) * 72 +
                                                            quad * 8 + 32 * kc];

        // S^T 32-key step: D[key][q]
        f32x4 S[2][2];
        #pragma unroll
        for (int m = 0; m < 2; ++m)
            #pragma unroll
            for (int n = 0; n < 2; ++n) S[m][n] = (f32x4){0.f, 0.f, 0.f, 0.f};

        __builtin_amdgcn_s_setprio(1);
        #pragma unroll
        for (int m2 = 0; m2 < 2; ++m2)
            #pragma unroll
            for (int cc = 0; cc < 2; ++cc)
                #pragma unroll
                for (int n = 0; n < 2; ++n)
                    S[m2][n] = __builtin_amdgcn_mfma_f32_16x16x32_bf16(kd[2 * m2 + cc],
                                                                       qf[n][cc], S[m2][n],
                                                                       0, 0, 0);
        __builtin_amdgcn_s_setprio(0);

        // mid-body: retire staging regs into the OTHER buffer (safe: all
        // reads of that buffer completed before the last barrier)
        if (pre) {
            *(ushort8*)&ldsK[cur ^ 1][sk_off] = nK;
            uint32x4 v4 = *(uint32x4*)&nV;
            *(uint2*)&ldsV[cur ^ 1][sv_b0] = make_uint2(v4.x, v4.y);
            *(uint2*)&ldsV[cur ^ 1][sv_b1] = make_uint2(v4.z, v4.w);
        }

        // V^T fragments (A[ch][pos]) from LDS (permuted key-positions)
        short8 vf[4];
        #pragma unroll
        for (int mc = 0; mc < 4; ++mc)
            vf[mc] = *(const short8*)&ldsV[cur][(16 * mc + l15) * 40 + quad * 8];

        // softmax numerators in-register: p = exp2(s - FM); pack into the PV
        // B fragment directly (lane's 8 values are its own quad's key block).
        #pragma unroll
        for (int n = 0; n < 2; ++n) {
            float e00 = __builtin_amdgcn_exp2f(S[0][n][0] - FM);
            float e01 = __builtin_amdgcn_exp2f(S[0][n][1] - FM);
            float e02 = __builtin_amdgcn_exp2f(S[0][n][2] - FM);
            float e03 = __builtin_amdgcn_exp2f(S[0][n][3] - FM);
            float e10 = __builtin_amdgcn_exp2f(S[1][n][0] - FM);
            float e11 = __builtin_amdgcn_exp2f(S[1][n][1] - FM);
            float e12 = __builtin_amdgcn_exp2f(S[1][n][2] - FM);
            float e13 = __builtin_amdgcn_exp2f(S[1][n][3] - FM);
            lrun[n] += ((e00 + e01) + (e02 + e03)) + ((e10 + e11) + (e12 + e13));
            uint32x4 w;
            w.x = pack_bf(e00, e01); w.y = pack_bf(e02, e03);
            w.z = pack_bf(e10, e11); w.w = pack_bf(e12, e13);
            short8 bfr = *(short8*)&w;

            __builtin_amdgcn_s_setprio(1);
            #pragma unroll
            for (int mc = 0; mc < 4; ++mc)
                O[mc][n] = __builtin_amdgcn_mfma_f32_16x16x32_bf16(vf[mc], bfr,
                                                                   O[mc][n], 0, 0, 0);
            __builtin_amdgcn_s_setprio(0);
        }

        __syncthreads();
    }

    #pragma unroll
    for (int n = 0; n < 2; ++n) {       // disjoint key subsets per quad
        lrun[n] += __shfl_xor(lrun[n], 16, 64);
        lrun[n] += __shfl_xor(lrun[n], 32, 64);
    }
    size_t bp = (size_t)b * P + p;
    if (quad == 0) {
        #pragma unroll
        for (int n = 0; n < 2; ++n)
            pl[bp * NPIX + qwave + 16 * n + l15] = lrun[n];
    }
    // pacc[b][p][c][n]: per (n,m,r) scalar 2B stores; across l15 lanes each
    // (m,r) is a 32B contiguous segment -> sector-aligned.
    #pragma unroll
    for (int n = 0; n < 2; ++n) {
        int qg = qwave + 16 * n + l15;
        #pragma unroll
        for (int m = 0; m < 4; ++m) {
            #pragma unroll
            for (int r = 0; r < 4; ++r) {
                int c = 16 * m + quad * 4 + r;
                pacc[(bp * NCH + c) * NPIX + qg] = f2bf_rne(O[m][n][r]);
            }
        }
    }
}

// ---------------------------------------------------------------------------
// Kernel 3b: Linv[b][n] = 0.2 / sum_p pl[b][p][n]
// ---------------------------------------------------------------------------
__global__ void k_norm(const float* __restrict__ pl, float* __restrict__ linv, int P) {
    int idx = blockIdx.x * blockDim.x + threadIdx.x;
    if (idx >= TOTPIX) return;
    int b = idx / NPIX, n = idx % NPIX;
    float L = 0.f;
    for (int p = 0; p < P; ++p) L += pl[((size_t)b * P + p) * NPIX + n];
    linv[idx] = 0.2f / L;
}

// ---------------------------------------------------------------------------
// Kernel 4: fully-coalesced combine. thread = (b, c, 8-n segment):
// o[n] = sum_p pacc[b][p][c][n] (ushort8 rows), out = x + Linv[n]*o[n].
// ---------------------------------------------------------------------------
__global__ void k_combine(const float* __restrict__ x, const float* __restrict__ linv,
                          const ushort* __restrict__ pacc, float* __restrict__ out,
                          int P) {
    int gid = blockIdx.x * blockDim.x + threadIdx.x;   // (b*NCH + c)*1152 + seg
    if (gid >= BB * NCH * (NPIX / 8)) return;
    int seg = gid % (NPIX / 8);
    int bc  = gid / (NPIX / 8);
    int b = bc / NCH;
    int n0 = seg * 8;
    float o[8] = {0.f, 0.f, 0.f, 0.f, 0.f, 0.f, 0.f, 0.f};
    for (int p = 0; p < P; ++p) {
        ushort8 t = *(const ushort8*)(pacc +
            (((size_t)b * P + p) * NCH + (bc % NCH)) * NPIX + n0);
        #pragma unroll
        for (int e = 0; e < 8; ++e) o[e] += bf2f(t[e]);
    }
    const float* lv = linv + (size_t)b * NPIX + n0;
    const float* xb = x + (size_t)bc * NPIX + n0;
    float* ob = out + (size_t)bc * NPIX + n0;
    #pragma unroll
    for (int e = 0; e < 8; ++e)
        ob[e] = fmaf(lv[e], o[e], xb[e]);
}

// ---------------------------------------------------------------------------
extern "C" void kernel_launch(void* const* d_in, const int* in_sizes, int n_in,
                              void* d_out, int out_size, void* d_ws, size_t ws_size,
                              hipStream_t stream) {
    const float* x      = (const float*)d_in[0];
    const float* w_red  = (const float*)d_in[1];
    const float* b_red  = (const float*)d_in[2];
    const float* w_dil  = (const float*)d_in[3];
    const float* b_dil  = (const float*)d_in[4];
    const float* w_fuse = (const float*)d_in[5];
    const float* b_fuse = (const float*)d_in[6];
    float* out = (float*)d_out;

    // ws: xred f32 | FT bf16 | tok bf16 | tokTt bf16 | pl f32 | linv f32 | pacc bf16
    const size_t XRED_N = (size_t)BB * INNER * NPIX;
    const size_t FT_N   = (size_t)64 * TOTPIX;
    const size_t TOK_N  = (size_t)BB * NPIX * NCH;
    const size_t HEAD_B = XRED_N * 4 + (FT_N + 2 * TOK_N) * 2 + TOTPIX * 4;
    int P = 0;
    // KP = NPIX/P must be a multiple of 32 (tile size). P=16 -> KP=576.
    const int cands[5] = {16, 8, 4, 2, 1};
    for (int ci = 0; ci < 5; ++ci) {
        int cp = cands[ci];
        size_t need = HEAD_B + (size_t)BB * cp * NPIX * (4 + NCH * 2);
        if (ws_size >= need) { P = cp; break; }
    }
    if (P == 0) return;

    float*  xred  = (float*)d_ws;
    ushort* FT    = (ushort*)(xred + XRED_N);
    ushort* tok   = FT + FT_N;
    ushort* tokTt = tok + TOK_N;
    float*  pl    = (float*)(tokTt + TOK_N);
    float*  linv  = pl + (size_t)BB * P * NPIX;
    ushort* pacc  = (ushort*)(linv + TOTPIX);

    k_reduce <<<(TOTPIX + 255) / 256, 256, 0, stream>>>(x, w_red, b_red, xred);
    k_feat   <<<3 * TOTPIX / 256, 256, 0, stream>>>(xred, w_dil, b_dil, FT);
    k_fuse   <<<TOTPIX / 64, 256, 0, stream>>>(FT, w_fuse, b_fuse, tok, tokTt);
    k_attn   <<<BB * P * (NPIX / 128), 256, 0, stream>>>(tok, tokTt, pl, pacc,
                                                         P, NPIX / P);
    k_norm   <<<(TOTPIX + 255) / 256, 256, 0, stream>>>(pl, linv, P);
    k_combine<<<(BB * NCH * (NPIX / 8) + 255) / 256, 256, 0, stream>>>(x, linv, pacc,
                                                                       out, P);
}

// Round 7
// 145.991 us; speedup vs baseline: 1.3930x; 1.0213x over previous
//
#include <hip/hip_runtime.h>

#define HW    96
#define NPIX  9216        // 96*96
#define NCH   64          // C
#define INNER 3
#define NDIL  3
#define BB    2           // batch
#define TOTPIX (BB * NPIX)   // 18432
#define NT32  (NPIX / 32)    // 288 key tiles per batch

typedef __attribute__((ext_vector_type(8))) short short8;            // 8 bf16
typedef __attribute__((ext_vector_type(8))) unsigned short ushort8;  // 8 bf16 raw
typedef __attribute__((ext_vector_type(4))) float f32x4;
typedef __attribute__((ext_vector_type(4))) unsigned int uint32x4;

__device__ __forceinline__ ushort f2bf_rne(float f) {
    unsigned u = __float_as_uint(f);
    u += 0x7fffu + ((u >> 16) & 1u);
    return (ushort)(u >> 16);
}
__device__ __forceinline__ float bf2f(ushort u) {
    return __uint_as_float((unsigned)u << 16);
}
// pack hi16(a),hi16(b) -> dword {bf16(b)<<16 | bf16(a)} (trunc; ratio-safe for P)
__device__ __forceinline__ unsigned pack_bf(float lo, float hi) {
    return __builtin_amdgcn_perm(__float_as_uint(hi), __float_as_uint(lo), 0x07060302u);
}

// ---------------------------------------------------------------------------
// Kernel 1: x_red = 1x1 conv (64 -> 3 channels). R7: 4-way channel split +
// LDS reduce. Old: 72 blocks (0.28/CU), 64-load serial chain per thread ->
// latency-bound. New: 288 blocks, 16-load chain, 4.5x threads.
// ---------------------------------------------------------------------------
__global__ __launch_bounds__(256) void
k_reduce(const float* __restrict__ x, const float* __restrict__ w_red,
         const float* __restrict__ b_red, float* __restrict__ xred) {
    __shared__ float part[4][3][64];
    int tid = threadIdx.x;
    int cp = tid >> 6, lane = tid & 63;
    int pix = blockIdx.x * 64 + lane;           // block never straddles b
    int b = pix / NPIX, n = pix % NPIX;
    const float* xb = x + (size_t)b * NCH * NPIX + (size_t)(cp * 16) * NPIX + n;
    float a0 = 0.f, a1 = 0.f, a2 = 0.f;
    #pragma unroll
    for (int c = 0; c < 16; ++c) {
        float xv = xb[(size_t)c * NPIX];
        a0 = fmaf(w_red[0 * NCH + cp * 16 + c], xv, a0);
        a1 = fmaf(w_red[1 * NCH + cp * 16 + c], xv, a1);
        a2 = fmaf(w_red[2 * NCH + cp * 16 + c], xv, a2);
    }
    part[cp][0][lane] = a0; part[cp][1][lane] = a1; part[cp][2][lane] = a2;
    __syncthreads();
    if (tid < 192) {
        int o = tid >> 6, lp = tid & 63;
        float s = ((part[0][o][lp] + part[1][o][lp]) +
                   (part[2][o][lp] + part[3][o][lp])) + b_red[o];
        int pix2 = blockIdx.x * 64 + lp;
        int b2 = pix2 / NPIX, n2 = pix2 % NPIX;
        xred[((size_t)b2 * INNER + o) * NPIX + n2] = s;
    }
}

// ---------------------------------------------------------------------------
// Kernel 2a: features. R7: thread = (pixel, dilation i3, out-channel o) ->
// 9*TOTPIX threads (648 blocks, ~2.5 waves/SIMD) vs old 216 blocks at
// ~1 wave/SIMD. Conv loads stay coalesced (xred L2-resident); tf loads drop
// 18 -> 6 per thread. Writes FT[j][pix] bf16, j = i3*18 + t*3 + o.
// Rows 54..63 never written — zero-weighted in k_fuse.
// ---------------------------------------------------------------------------
__global__ __launch_bounds__(256) void
k_feat(const float* __restrict__ xred, const float* __restrict__ w_dil,
       const float* __restrict__ b_dil, ushort* __restrict__ FT) {
    int gid = blockIdx.x * 256 + threadIdx.x;      // 9 * 18432 threads exactly
    int io = gid / TOTPIX;                          // wave-uniform (TOTPIX%64==0)
    int pix = gid - io * TOTPIX;
    int i3 = io / 3, o = io - 3 * i3;
    int b = pix / NPIX, n = pix % NPIX;
    int h = n / HW, w = n % HW;
    const float* xr = xred + (size_t)b * INNER * NPIX;
    int d = i3 + 1;

    float co = b_dil[i3 * 3 + o];
    #pragma unroll
    for (int ci = 0; ci < 3; ++ci) {
        const float* xo = xr + ci * NPIX;
        #pragma unroll
        for (int kh = 0; kh < 3; ++kh) {
            int hh = h + (kh - 1) * d;
            #pragma unroll
            for (int kw = 0; kw < 3; ++kw) {
                int ww = w + (kw - 1) * d;
                float v = ((unsigned)hh < HW && (unsigned)ww < HW) ? xo[hh * HW + ww] : 0.f;
                co = fmaf(w_dil[(9 * i3 + 3 * o + ci) * 9 + kh * 3 + kw], v, co);
            }
        }
    }

    const float* xo = xr + o * NPIX;
    float tf0 = xo[h * HW + w];
    float tf1 = xo[h * HW + (HW - 1 - w)];
    float tf2 = xo[(HW - 1 - h) * HW + w];
    float tf3 = xo[w * HW + (HW - 1 - h)];
    float tf4 = xo[(HW - 1 - h) * HW + (HW - 1 - w)];
    float tf5 = xo[(HW - 1 - w) * HW + h];

    size_t base = (size_t)(i3 * 18 + o) * TOTPIX + pix;
    FT[base + (size_t)(0 * 3) * TOTPIX] = f2bf_rne(co * tf0);
    FT[base + (size_t)(1 * 3) * TOTPIX] = f2bf_rne(co * tf1);
    FT[base + (size_t)(2 * 3) * TOTPIX] = f2bf_rne(co * tf2);
    FT[base + (size_t)(3 * 3) * TOTPIX] = f2bf_rne(co * tf3);
    FT[base + (size_t)(4 * 3) * TOTPIX] = f2bf_rne(co * tf4);
    FT[base + (size_t)(5 * 3) * TOTPIX] = f2bf_rne(co * tf5);
}

// ---------------------------------------------------------------------------
// Kernel 2b: fuse conv as MFMA GEMM, 64 px/block (grid 288).
// tokT is TILED: [b][n>>5][c][n&31] so k_attn's V staging is contiguous.
// ---------------------------------------------------------------------------
__global__ __launch_bounds__(256) void
k_fuse(const ushort* __restrict__ FT, const float* __restrict__ w_fuse,
       const float* __restrict__ b_fuse, ushort* __restrict__ tok,
       ushort* __restrict__ tokTt) {
    __shared__ ushort wpad[64 * 72];     // [c][j pad 72]
    __shared__ float  bsh[64];
    __shared__ ushort tile[64 * 72];     // [c][64 px + 8 pad]

    int tid = threadIdx.x;
    for (int i = tid; i < 64 * 64; i += 256) {
        int c = i >> 6, j = i & 63;
        wpad[c * 72 + j] = (j < 54) ? f2bf_rne(w_fuse[c * 54 + j]) : (ushort)0;
    }
    if (tid < 64) bsh[tid] = b_fuse[tid];
    __syncthreads();

    int wv = tid >> 6, lane = tid & 63, quad = lane >> 4, l15 = lane & 15;
    int px0 = blockIdx.x * 64;

    short8 af[4][2];
    #pragma unroll
    for (int m = 0; m < 4; ++m)
        #pragma unroll
        for (int kc = 0; kc < 2; ++kc)
            af[m][kc] = *(const short8*)&wpad[(16 * m + l15) * 72 + quad * 8 + 32 * kc];

    f32x4 acc[4];
    #pragma unroll
    for (int m = 0; m < 4; ++m) acc[m] = (f32x4){0.f, 0.f, 0.f, 0.f};

    int px = px0 + wv * 16 + l15;
    #pragma unroll
    for (int kc = 0; kc < 2; ++kc) {
        short8 bf;
        #pragma unroll
        for (int jj = 0; jj < 8; ++jj)
            bf[jj] = (short)FT[(size_t)(quad * 8 + jj + 32 * kc) * TOTPIX + px];
        #pragma unroll
        for (int m = 0; m < 4; ++m)
            acc[m] = __builtin_amdgcn_mfma_f32_16x16x32_bf16(af[m][kc], bf, acc[m], 0, 0, 0);
    }

    #pragma unroll
    for (int m = 0; m < 4; ++m)
        #pragma unroll
        for (int r = 0; r < 4; ++r) {
            int c = 16 * m + quad * 4 + r;
            tile[c * 72 + wv * 16 + l15] = f2bf_rne(acc[m][r] + bsh[c]);
        }
    __syncthreads();

    int b0 = px0 / NPIX, n0 = px0 % NPIX;
    {   // tok[b][n][c]
        int lp = tid >> 2, part = tid & 3;
        ushort row[16];
        #pragma unroll
        for (int k = 0; k < 16; ++k) row[k] = tile[(part * 16 + k) * 72 + lp];
        ushort* dst = tok + ((size_t)b0 * NPIX + n0 + lp) * NCH + part * 16;
        *(ushort8*)&dst[0] = *(const ushort8*)&row[0];
        *(ushort8*)&dst[8] = *(const ushort8*)&row[8];
    }
    {   // tokTt[b][n>>5][c][n&31] (32-key tiles)
        int c = tid >> 2, seg = tid & 3;
        int n = n0 + seg * 16;
        size_t base = (((size_t)b0 * NT32 + (n >> 5)) * 64 + c) * 32 + (n & 31);
        *(ushort8*)&tokTt[base]     = *(const ushort8*)&tile[c * 72 + seg * 16];
        *(ushort8*)&tokTt[base + 8] = *(const ushort8*)&tile[c * 72 + seg * 16 + 8];
    }
}

// ---------------------------------------------------------------------------
// Kernel 3: MFMA flash attention, IN-REGISTER P (no pt LDS round-trip).
// S^T output of lane (quad,l15) holds P for ITS OWN quad's key block; under
// the key re-ordering pos = 8*quad + 4*m2 + reg, the packed S fragment IS the
// PV B-operand fragment. The permutation is folded into the V staging LDS
// offsets. K staging cooperative + double-buffered (R4), 32 q/wave (R5).
// ---------------------------------------------------------------------------
__global__ __launch_bounds__(256, 4) void
k_attn(const ushort* __restrict__ tok, const ushort* __restrict__ tokTt,
       float* __restrict__ pl, ushort* __restrict__ pacc, int P, int KP) {
    __shared__ ushort ldsK[2][32 * 72];    // [key][64ch + 8 pad], 2 x 4.5 KB
    __shared__ ushort ldsV[2][64 * 40];    // [ch][32pos + 8 pad], 2 x 5 KB

    const int QW = NPIX / 128;          // 72 query chunks per batch
    int bid = blockIdx.x;
    int qc = bid % QW; int rest = bid / QW;
    int p = rest % P;  int b = rest / P;
    int tid = threadIdx.x;
    int wv = tid >> 6, lane = tid & 63;
    int quad = lane >> 4, l15 = lane & 15;

    const ushort* tb  = tok + (size_t)b * NPIX * NCH;
    const ushort* tvb = tokTt + (size_t)b * NT32 * (64 * 32);
    int qwave = qc * 128 + wv * 32;

    // staging decomposition (per thread: one 16B chunk of each tile)
    int sk_off = (tid >> 3) * 72 + (tid & 7) * 8;   // [key=tid>>3][ch=(tid&7)*8]
    // V: thread stages ch=tid>>2, keys kk=(tid&3)*8+e. Permuted destination:
    // e=0..3 -> pos base0+e, e=4..7 -> pos base1+(e&3)  (bijective, verified)
    int svj = tid & 3;
    int sv_b0 = (tid >> 2) * 40 + 8 * ((2 * svj) & 3) + 4 * (svj >> 1);
    int sv_b1 = (tid >> 2) * 40 + 8 * ((2 * svj + 1) & 3) + 4 * (svj >> 1);

    // Q fragments: B operand of S^T (lane q=16n+l15, k=quad*8+j+32kc); scale folded.
    short8 qf[2][2];
    const float scale = 0.125f * 1.44269504088896340736f;  // 1/sqrt(C) * log2(e)
    #pragma unroll
    for (int n = 0; n < 2; ++n) {
        const ushort* qr = tb + (size_t)(qwave + 16 * n + l15) * NCH + quad * 8;
        #pragma unroll
        for (int kc = 0; kc < 2; ++kc) {
            ushort8 raw = *(const ushort8*)(qr + 32 * kc);
            short8 f;
            #pragma unroll
            for (int e = 0; e < 8; ++e) f[e] = (short)f2bf_rne(bf2f(raw[e]) * scale);
            qf[n][kc] = f;
        }
    }

    f32x4 O[4][2];                      // O^T acc: D[c=16m+quad*4+reg][q=16n+l15]
    #pragma unroll
    for (int m = 0; m < 4; ++m)
        #pragma unroll
        for (int n = 0; n < 2; ++n) O[m][n] = (f32x4){0.f, 0.f, 0.f, 0.f};
    float lrun[2] = {0.f, 0.f};

    const float FM = 16.0f;             // fixed exp2-domain shift
    int k0 = p * KP;
    int nt = KP / 32;

    // prologue: stage tile 0
    {
        ushort8 gK = *(const ushort8*)(tb + (size_t)k0 * NCH + tid * 8);
        ushort8 gV = *(const ushort8*)(tvb + ((size_t)(k0 >> 5)) * 2048 + tid * 8);
        *(ushort8*)&ldsK[0][sk_off] = gK;
        uint32x4 v4 = *(uint32x4*)&gV;
        *(uint2*)&ldsV[0][sv_b0] = make_uint2(v4.x, v4.y);
        *(uint2*)&ldsV[0][sv_b1] = make_uint2(v4.z, v4.w);
    }
    __syncthreads();

    for (int t = 0; t < nt; ++t) {
        int cur = t & 1;
        int kbase = k0 + t * 32;
        bool pre = (t + 1 < nt);

        // issue next tile's global loads EARLY (latency hides under S phase)
        ushort8 nK, nV;
        if (pre) {
            nK = *(const ushort8*)(tb + (size_t)(kbase + 32) * NCH + tid * 8);
            nV = *(const ushort8*)(tvb + ((size_t)((kbase + 32) >> 5)) * 2048 + tid * 8);
        }

        // K fragments from LDS (shared by all 4 waves)
        short8 kd[4];
        #pragma unroll
        for (int m2 = 0; m2 < 2; ++m2)
            #pragma unroll
            for (int kc = 0; kc < 2; ++kc)
                kd[2 * m2 + kc] = *(const short8*)&ldsK[cur][(16 * m2 + l15) * 72 +
                                                            quad * 8 + 32 * kc];

        // S^T 32-key step: D[key][q]
        f32x4 S[2][2];
        #pragma unroll
        for (int m = 0; m < 2; ++m)
            #pragma unroll
            for (int n = 0; n < 2; ++n) S[m][n] = (f32x4){0.f, 0.f, 0.f, 0.f};

        __builtin_amdgcn_s_setprio(1);
        #pragma unroll
        for (int m2 = 0; m2 < 2; ++m2)
            #pragma unroll
            for (int cc = 0; cc < 2; ++cc)
                #pragma unroll
                for (int n = 0; n < 2; ++n)
                    S[m2][n] = __builtin_amdgcn_mfma_f32_16x16x32_bf16(kd[2 * m2 + cc],
                                                                       qf[n][cc], S[m2][n],
                                                                       0, 0, 0);
        __builtin_amdgcn_s_setprio(0);

        // mid-body: retire staging regs into the OTHER buffer (safe: all
        // reads of that buffer completed before the last barrier)
        if (pre) {
            *(ushort8*)&ldsK[cur ^ 1][sk_off] = nK;
            uint32x4 v4 = *(uint32x4*)&nV;
            *(uint2*)&ldsV[cur ^ 1][sv_b0] = make_uint2(v4.x, v4.y);
            *(uint2*)&ldsV[cur ^ 1][sv_b1] = make_uint2(v4.z, v4.w);
        }

        // V^T fragments (A[ch][pos]) from LDS (permuted key-positions)
        short8 vf[4];
        #pragma unroll
        for (int mc = 0; mc < 4; ++mc)
            vf[mc] = *(const short8*)&ldsV[cur][(16 * mc + l15) * 40 + quad * 8];

        // softmax numerators in-register: p = exp2(s - FM); pack into the PV
        // B fragment directly (lane's 8 values are its own quad's key block).
        #pragma unroll
        for (int n = 0; n < 2; ++n) {
            float e00 = __builtin_amdgcn_exp2f(S[0][n][0] - FM);
            float e01 = __builtin_amdgcn_exp2f(S[0][n][1] - FM);
            float e02 = __builtin_amdgcn_exp2f(S[0][n][2] - FM);
            float e03 = __builtin_amdgcn_exp2f(S[0][n][3] - FM);
            float e10 = __builtin_amdgcn_exp2f(S[1][n][0] - FM);
            float e11 = __builtin_amdgcn_exp2f(S[1][n][1] - FM);
            float e12 = __builtin_amdgcn_exp2f(S[1][n][2] - FM);
            float e13 = __builtin_amdgcn_exp2f(S[1][n][3] - FM);
            lrun[n] += ((e00 + e01) + (e02 + e03)) + ((e10 + e11) + (e12 + e13));
            uint32x4 w;
            w.x = pack_bf(e00, e01); w.y = pack_bf(e02, e03);
            w.z = pack_bf(e10, e11); w.w = pack_bf(e12, e13);
            short8 bfr = *(short8*)&w;

            __builtin_amdgcn_s_setprio(1);
            #pragma unroll
            for (int mc = 0; mc < 4; ++mc)
                O[mc][n] = __builtin_amdgcn_mfma_f32_16x16x32_bf16(vf[mc], bfr,
                                                                   O[mc][n], 0, 0, 0);
            __builtin_amdgcn_s_setprio(0);
        }

        __syncthreads();
    }

    #pragma unroll
    for (int n = 0; n < 2; ++n) {       // disjoint key subsets per quad
        lrun[n] += __shfl_xor(lrun[n], 16, 64);
        lrun[n] += __shfl_xor(lrun[n], 32, 64);
    }
    size_t bp = (size_t)b * P + p;
    if (quad == 0) {
        #pragma unroll
        for (int n = 0; n < 2; ++n)
            pl[bp * NPIX + qwave + 16 * n + l15] = lrun[n];
    }
    // pacc[b][p][c][n]: per (n,m,r) scalar 2B stores; across l15 lanes each
    // (m,r) is a 32B contiguous segment -> sector-aligned.
    #pragma unroll
    for (int n = 0; n < 2; ++n) {
        int qg = qwave + 16 * n + l15;
        #pragma unroll
        for (int m = 0; m < 4; ++m) {
            #pragma unroll
            for (int r = 0; r < 4; ++r) {
                int c = 16 * m + quad * 4 + r;
                pacc[(bp * NCH + c) * NPIX + qg] = f2bf_rne(O[m][n][r]);
            }
        }
    }
}

// ---------------------------------------------------------------------------
// Kernel 3b: Linv[b][n] = 0.2 / sum_p pl[b][p][n]
// ---------------------------------------------------------------------------
__global__ void k_norm(const float* __restrict__ pl, float* __restrict__ linv, int P) {
    int idx = blockIdx.x * blockDim.x + threadIdx.x;
    if (idx >= TOTPIX) return;
    int b = idx / NPIX, n = idx % NPIX;
    float L = 0.f;
    for (int p = 0; p < P; ++p) L += pl[((size_t)b * P + p) * NPIX + n];
    linv[idx] = 0.2f / L;
}

// ---------------------------------------------------------------------------
// Kernel 4: fully-coalesced combine. thread = (b, c, 8-n segment):
// o[n] = sum_p pacc[b][p][c][n] (ushort8 rows), out = x + Linv[n]*o[n].
// ---------------------------------------------------------------------------
__global__ void k_combine(const float* __restrict__ x, const float* __restrict__ linv,
                          const ushort* __restrict__ pacc, float* __restrict__ out,
                          int P) {
    int gid = blockIdx.x * blockDim.x + threadIdx.x;   // (b*NCH + c)*1152 + seg
    if (gid >= BB * NCH * (NPIX / 8)) return;
    int seg = gid % (NPIX / 8);
    int bc  = gid / (NPIX / 8);
    int b = bc / NCH;
    int n0 = seg * 8;
    float o[8] = {0.f, 0.f, 0.f, 0.f, 0.f, 0.f, 0.f, 0.f};
    for (int p = 0; p < P; ++p) {
        ushort8 t = *(const ushort8*)(pacc +
            (((size_t)b * P + p) * NCH + (bc % NCH)) * NPIX + n0);
        #pragma unroll
        for (int e = 0; e < 8; ++e) o[e] += bf2f(t[e]);
    }
    const float* lv = linv + (size_t)b * NPIX + n0;
    const float* xb = x + (size_t)bc * NPIX + n0;
    float* ob = out + (size_t)bc * NPIX + n0;
    #pragma unroll
    for (int e = 0; e < 8; ++e)
        ob[e] = fmaf(lv[e], o[e], xb[e]);
}

// ---------------------------------------------------------------------------
extern "C" void kernel_launch(void* const* d_in, const int* in_sizes, int n_in,
                              void* d_out, int out_size, void* d_ws, size_t ws_size,
                              hipStream_t stream) {
    const float* x      = (const float*)d_in[0];
    const float* w_red  = (const float*)d_in[1];
    const float* b_red  = (const float*)d_in[2];
    const float* w_dil  = (const float*)d_in[3];
    const float* b_dil  = (const float*)d_in[4];
    const float* w_fuse = (const float*)d_in[5];
    const float* b_fuse = (const float*)d_in[6];
    float* out = (float*)d_out;

    // ws: xred f32 | FT bf16 | tok bf16 | tokTt bf16 | pl f32 | linv f32 | pacc bf16
    const size_t XRED_N = (size_t)BB * INNER * NPIX;
    const size_t FT_N   = (size_t)64 * TOTPIX;
    const size_t TOK_N  = (size_t)BB * NPIX * NCH;
    const size_t HEAD_B = XRED_N * 4 + (FT_N + 2 * TOK_N) * 2 + TOTPIX * 4;
    int P = 0;
    // KP = NPIX/P must be a multiple of 32 (tile size). P=16 -> KP=576.
    const int cands[5] = {16, 8, 4, 2, 1};
    for (int ci = 0; ci < 5; ++ci) {
        int cp = cands[ci];
        size_t need = HEAD_B + (size_t)BB * cp * NPIX * (4 + NCH * 2);
        if (ws_size >= need) { P = cp; break; }
    }
    if (P == 0) return;

    float*  xred  = (float*)d_ws;
    ushort* FT    = (ushort*)(xred + XRED_N);
    ushort* tok   = FT + FT_N;
    ushort* tokTt = tok + TOK_N;
    float*  pl    = (float*)(tokTt + TOK_N);
    float*  linv  = pl + (size_t)BB * P * NPIX;
    ushort* pacc  = (ushort*)(linv + TOTPIX);

    k_reduce <<<TOTPIX / 64, 256, 0, stream>>>(x, w_red, b_red, xred);
    k_feat   <<<9 * TOTPIX / 256, 256, 0, stream>>>(xred, w_dil, b_dil, FT);
    k_fuse   <<<TOTPIX / 64, 256, 0, stream>>>(FT, w_fuse, b_fuse, tok, tokTt);
    k_attn   <<<BB * P * (NPIX / 128), 256, 0, stream>>>(tok, tokTt, pl, pacc,
                                                         P, NPIX / P);
    k_norm   <<<(TOTPIX + 255) / 256, 256, 0, stream>>>(pl, linv, P);
    k_combine<<<(BB * NCH * (NPIX / 8) + 255) / 256, 256, 0, stream>>>(x, linv, pacc,
                                                                       out, P);
}

// Round 8
// 143.669 us; speedup vs baseline: 1.4155x; 1.0162x over previous
//
#include <hip/hip_runtime.h>

#define HW    96
#define NPIX  9216        // 96*96
#define NCH   64          // C
#define INNER 3
#define NDIL  3
#define BB    2           // batch
#define TOTPIX (BB * NPIX)   // 18432
#define NT32  (NPIX / 32)    // 288 key tiles per batch

typedef __attribute__((ext_vector_type(8))) short short8;            // 8 bf16
typedef __attribute__((ext_vector_type(8))) unsigned short ushort8;  // 8 bf16 raw
typedef __attribute__((ext_vector_type(4))) float f32x4;
typedef __attribute__((ext_vector_type(4))) unsigned int uint32x4;

__device__ __forceinline__ ushort f2bf_rne(float f) {
    unsigned u = __float_as_uint(f);
    u += 0x7fffu + ((u >> 16) & 1u);
    return (ushort)(u >> 16);
}
__device__ __forceinline__ float bf2f(ushort u) {
    return __uint_as_float((unsigned)u << 16);
}
// pack hi16(a),hi16(b) -> dword {bf16(b)<<16 | bf16(a)} (trunc; ratio-safe for P)
__device__ __forceinline__ unsigned pack_bf(float lo, float hi) {
    return __builtin_amdgcn_perm(__float_as_uint(hi), __float_as_uint(lo), 0x07060302u);
}

// ---------------------------------------------------------------------------
// Kernel 1: x_red = 1x1 conv (64 -> 3 channels). 4-way channel split +
// LDS reduce (R7).
// ---------------------------------------------------------------------------
__global__ __launch_bounds__(256) void
k_reduce(const float* __restrict__ x, const float* __restrict__ w_red,
         const float* __restrict__ b_red, float* __restrict__ xred) {
    __shared__ float part[4][3][64];
    int tid = threadIdx.x;
    int cp = tid >> 6, lane = tid & 63;
    int pix = blockIdx.x * 64 + lane;           // block never straddles b
    int b = pix / NPIX, n = pix % NPIX;
    const float* xb = x + (size_t)b * NCH * NPIX + (size_t)(cp * 16) * NPIX + n;
    float a0 = 0.f, a1 = 0.f, a2 = 0.f;
    #pragma unroll
    for (int c = 0; c < 16; ++c) {
        float xv = xb[(size_t)c * NPIX];
        a0 = fmaf(w_red[0 * NCH + cp * 16 + c], xv, a0);
        a1 = fmaf(w_red[1 * NCH + cp * 16 + c], xv, a1);
        a2 = fmaf(w_red[2 * NCH + cp * 16 + c], xv, a2);
    }
    part[cp][0][lane] = a0; part[cp][1][lane] = a1; part[cp][2][lane] = a2;
    __syncthreads();
    if (tid < 192) {
        int o = tid >> 6, lp = tid & 63;
        float s = ((part[0][o][lp] + part[1][o][lp]) +
                   (part[2][o][lp] + part[3][o][lp])) + b_red[o];
        int pix2 = blockIdx.x * 64 + lp;
        int b2 = pix2 / NPIX, n2 = pix2 % NPIX;
        xred[((size_t)b2 * INNER + o) * NPIX + n2] = s;
    }
}

// ---------------------------------------------------------------------------
// Kernel 2a: features. thread = (pixel, dilation i3, out-channel o) (R7).
// Writes FT[j][pix] bf16, j = i3*18 + t*3 + o. Rows 54..63 never written —
// zero-weighted in k_fuse.
// ---------------------------------------------------------------------------
__global__ __launch_bounds__(256) void
k_feat(const float* __restrict__ xred, const float* __restrict__ w_dil,
       const float* __restrict__ b_dil, ushort* __restrict__ FT) {
    int gid = blockIdx.x * 256 + threadIdx.x;      // 9 * 18432 threads exactly
    int io = gid / TOTPIX;                          // wave-uniform (TOTPIX%64==0)
    int pix = gid - io * TOTPIX;
    int i3 = io / 3, o = io - 3 * i3;
    int b = pix / NPIX, n = pix % NPIX;
    int h = n / HW, w = n % HW;
    const float* xr = xred + (size_t)b * INNER * NPIX;
    int d = i3 + 1;

    float co = b_dil[i3 * 3 + o];
    #pragma unroll
    for (int ci = 0; ci < 3; ++ci) {
        const float* xo = xr + ci * NPIX;
        #pragma unroll
        for (int kh = 0; kh < 3; ++kh) {
            int hh = h + (kh - 1) * d;
            #pragma unroll
            for (int kw = 0; kw < 3; ++kw) {
                int ww = w + (kw - 1) * d;
                float v = ((unsigned)hh < HW && (unsigned)ww < HW) ? xo[hh * HW + ww] : 0.f;
                co = fmaf(w_dil[(9 * i3 + 3 * o + ci) * 9 + kh * 3 + kw], v, co);
            }
        }
    }

    const float* xo = xr + o * NPIX;
    float tf0 = xo[h * HW + w];
    float tf1 = xo[h * HW + (HW - 1 - w)];
    float tf2 = xo[(HW - 1 - h) * HW + w];
    float tf3 = xo[w * HW + (HW - 1 - h)];
    float tf4 = xo[(HW - 1 - h) * HW + (HW - 1 - w)];
    float tf5 = xo[(HW - 1 - w) * HW + h];

    size_t base = (size_t)(i3 * 18 + o) * TOTPIX + pix;
    FT[base + (size_t)(0 * 3) * TOTPIX] = f2bf_rne(co * tf0);
    FT[base + (size_t)(1 * 3) * TOTPIX] = f2bf_rne(co * tf1);
    FT[base + (size_t)(2 * 3) * TOTPIX] = f2bf_rne(co * tf2);
    FT[base + (size_t)(3 * 3) * TOTPIX] = f2bf_rne(co * tf3);
    FT[base + (size_t)(4 * 3) * TOTPIX] = f2bf_rne(co * tf4);
    FT[base + (size_t)(5 * 3) * TOTPIX] = f2bf_rne(co * tf5);
}

// ---------------------------------------------------------------------------
// Kernel 2b: fuse conv as MFMA GEMM, 64 px/block (grid 288).
// tokT is TILED: [b][n>>5][c][n&31] so k_attn's V staging is contiguous.
// ---------------------------------------------------------------------------
__global__ __launch_bounds__(256) void
k_fuse(const ushort* __restrict__ FT, const float* __restrict__ w_fuse,
       const float* __restrict__ b_fuse, ushort* __restrict__ tok,
       ushort* __restrict__ tokTt) {
    __shared__ ushort wpad[64 * 72];     // [c][j pad 72]
    __shared__ float  bsh[64];
    __shared__ ushort tile[64 * 72];     // [c][64 px + 8 pad]

    int tid = threadIdx.x;
    for (int i = tid; i < 64 * 64; i += 256) {
        int c = i >> 6, j = i & 63;
        wpad[c * 72 + j] = (j < 54) ? f2bf_rne(w_fuse[c * 54 + j]) : (ushort)0;
    }
    if (tid < 64) bsh[tid] = b_fuse[tid];
    __syncthreads();

    int wv = tid >> 6, lane = tid & 63, quad = lane >> 4, l15 = lane & 15;
    int px0 = blockIdx.x * 64;

    short8 af[4][2];
    #pragma unroll
    for (int m = 0; m < 4; ++m)
        #pragma unroll
        for (int kc = 0; kc < 2; ++kc)
            af[m][kc] = *(const short8*)&wpad[(16 * m + l15) * 72 + quad * 8 + 32 * kc];

    f32x4 acc[4];
    #pragma unroll
    for (int m = 0; m < 4; ++m) acc[m] = (f32x4){0.f, 0.f, 0.f, 0.f};

    int px = px0 + wv * 16 + l15;
    #pragma unroll
    for (int kc = 0; kc < 2; ++kc) {
        short8 bf;
        #pragma unroll
        for (int jj = 0; jj < 8; ++jj)
            bf[jj] = (short)FT[(size_t)(quad * 8 + jj + 32 * kc) * TOTPIX + px];
        #pragma unroll
        for (int m = 0; m < 4; ++m)
            acc[m] = __builtin_amdgcn_mfma_f32_16x16x32_bf16(af[m][kc], bf, acc[m], 0, 0, 0);
    }

    #pragma unroll
    for (int m = 0; m < 4; ++m)
        #pragma unroll
        for (int r = 0; r < 4; ++r) {
            int c = 16 * m + quad * 4 + r;
            tile[c * 72 + wv * 16 + l15] = f2bf_rne(acc[m][r] + bsh[c]);
        }
    __syncthreads();

    int b0 = px0 / NPIX, n0 = px0 % NPIX;
    {   // tok[b][n][c]
        int lp = tid >> 2, part = tid & 3;
        ushort row[16];
        #pragma unroll
        for (int k = 0; k < 16; ++k) row[k] = tile[(part * 16 + k) * 72 + lp];
        ushort* dst = tok + ((size_t)b0 * NPIX + n0 + lp) * NCH + part * 16;
        *(ushort8*)&dst[0] = *(const ushort8*)&row[0];
        *(ushort8*)&dst[8] = *(const ushort8*)&row[8];
    }
    {   // tokTt[b][n>>5][c][n&31] (32-key tiles)
        int c = tid >> 2, seg = tid & 3;
        int n = n0 + seg * 16;
        size_t base = (((size_t)b0 * NT32 + (n >> 5)) * 64 + c) * 32 + (n & 31);
        *(ushort8*)&tokTt[base]     = *(const ushort8*)&tile[c * 72 + seg * 16];
        *(ushort8*)&tokTt[base + 8] = *(const ushort8*)&tile[c * 72 + seg * 16 + 8];
    }
}

// ---------------------------------------------------------------------------
// Kernel 3: MFMA flash attention, in-register P (R6) + 5-WAVE OCCUPANCY (R8).
// R8: S computed per-m2 half (8 S regs instead of 16), MFMA C takes a
// persistent zero vector (no per-body re-zeroing), launch_bounds(256,5)
// (unified regs ~96 <= 512/5), pointer strength-reduction in the key loop,
// lrun accumulated into global L via atomicAdd (k_norm kernel eliminated;
// L is memset before launch).
// ---------------------------------------------------------------------------
__global__ __launch_bounds__(256, 5) void
k_attn(const ushort* __restrict__ tok, const ushort* __restrict__ tokTt,
       float* __restrict__ L, ushort* __restrict__ pacc, int P, int KP) {
    __shared__ ushort ldsK[2][32 * 72];    // [key][64ch + 8 pad], 2 x 4.5 KB
    __shared__ ushort ldsV[2][64 * 40];    // [ch][32pos + 8 pad], 2 x 5 KB

    const int QW = NPIX / 128;          // 72 query chunks per batch
    int bid = blockIdx.x;
    int qc = bid % QW; int rest = bid / QW;
    int p = rest % P;  int b = rest / P;
    int tid = threadIdx.x;
    int wv = tid >> 6, lane = tid & 63;
    int quad = lane >> 4, l15 = lane & 15;

    const ushort* tb  = tok + (size_t)b * NPIX * NCH;
    const ushort* tvb = tokTt + (size_t)b * NT32 * (64 * 32);
    int qwave = qc * 128 + wv * 32;

    // staging decomposition (per thread: one 16B chunk of each tile)
    int sk_off = (tid >> 3) * 72 + (tid & 7) * 8;   // [key=tid>>3][ch=(tid&7)*8]
    // V: thread stages ch=tid>>2, keys kk=(tid&3)*8+e. Permuted destination:
    // e=0..3 -> pos base0+e, e=4..7 -> pos base1+(e&3)  (bijective, verified)
    int svj = tid & 3;
    int sv_b0 = (tid >> 2) * 40 + 8 * ((2 * svj) & 3) + 4 * (svj >> 1);
    int sv_b1 = (tid >> 2) * 40 + 8 * ((2 * svj + 1) & 3) + 4 * (svj >> 1);

    // Q fragments: B operand of S^T (lane q=16n+l15, k=quad*8+j+32kc); scale folded.
    short8 qf[2][2];
    const float scale = 0.125f * 1.44269504088896340736f;  // 1/sqrt(C) * log2(e)
    #pragma unroll
    for (int n = 0; n < 2; ++n) {
        const ushort* qr = tb + (size_t)(qwave + 16 * n + l15) * NCH + quad * 8;
        #pragma unroll
        for (int kc = 0; kc < 2; ++kc) {
            ushort8 raw = *(const ushort8*)(qr + 32 * kc);
            short8 f;
            #pragma unroll
            for (int e = 0; e < 8; ++e) f[e] = (short)f2bf_rne(bf2f(raw[e]) * scale);
            qf[n][kc] = f;
        }
    }

    f32x4 O[4][2];                      // O^T acc: D[c=16m+quad*4+reg][q=16n+l15]
    #pragma unroll
    for (int m = 0; m < 4; ++m)
        #pragma unroll
        for (int n = 0; n < 2; ++n) O[m][n] = (f32x4){0.f, 0.f, 0.f, 0.f};
    float lrun[2] = {0.f, 0.f};
    const f32x4 Zc = (f32x4){0.f, 0.f, 0.f, 0.f};   // persistent MFMA C-zero

    const float FM = 16.0f;             // fixed exp2-domain shift
    int k0 = p * KP;
    int nt = KP / 32;

    // strength-reduced staging pointers (advance by one 32-key tile per body)
    const ushort* pK = tb + (size_t)k0 * NCH + tid * 8;
    const ushort* pV = tvb + ((size_t)(k0 >> 5)) * 2048 + tid * 8;

    // prologue: stage tile 0
    {
        ushort8 gK = *(const ushort8*)pK;
        ushort8 gV = *(const ushort8*)pV;
        *(ushort8*)&ldsK[0][sk_off] = gK;
        uint32x4 v4 = *(uint32x4*)&gV;
        *(uint2*)&ldsV[0][sv_b0] = make_uint2(v4.x, v4.y);
        *(uint2*)&ldsV[0][sv_b1] = make_uint2(v4.z, v4.w);
    }
    __syncthreads();

    for (int t = 0; t < nt; ++t) {
        int cur = t & 1;
        bool pre = (t + 1 < nt);
        pK += 32 * NCH;  pV += 2048;

        // issue next tile's global loads EARLY (latency hides under S phase)
        ushort8 nK, nV;
        if (pre) {
            nK = *(const ushort8*)pK;
            nV = *(const ushort8*)pV;
        }

        // K fragments from LDS (shared by all 4 waves)
        short8 kd[4];
        #pragma unroll
        for (int m2 = 0; m2 < 2; ++m2)
            #pragma unroll
            for (int kc = 0; kc < 2; ++kc)
                kd[2 * m2 + kc] = *(const short8*)&ldsK[cur][(16 * m2 + l15) * 72 +
                                                            quad * 8 + 32 * kc];

        // S^T per-m2 half: 4 MFMA -> 8 exp2 -> pack. S regs halved (8), and
        // m2=1's MFMAs overlap m2=0's exp chain.
        uint32x4 wac[2];
        #pragma unroll
        for (int m2 = 0; m2 < 2; ++m2) {
            f32x4 Sm[2];
            __builtin_amdgcn_s_setprio(1);
            #pragma unroll
            for (int n = 0; n < 2; ++n) {
                Sm[n] = __builtin_amdgcn_mfma_f32_16x16x32_bf16(kd[2 * m2 + 0],
                                                                qf[n][0], Zc, 0, 0, 0);
                Sm[n] = __builtin_amdgcn_mfma_f32_16x16x32_bf16(kd[2 * m2 + 1],
                                                                qf[n][1], Sm[n], 0, 0, 0);
            }
            __builtin_amdgcn_s_setprio(0);
            #pragma unroll
            for (int n = 0; n < 2; ++n) {
                float e0 = __builtin_amdgcn_exp2f(Sm[n][0] - FM);
                float e1 = __builtin_amdgcn_exp2f(Sm[n][1] - FM);
                float e2 = __builtin_amdgcn_exp2f(Sm[n][2] - FM);
                float e3 = __builtin_amdgcn_exp2f(Sm[n][3] - FM);
                lrun[n] += (e0 + e1) + (e2 + e3);
                if (m2 == 0) {
                    wac[n].x = pack_bf(e0, e1); wac[n].y = pack_bf(e2, e3);
                } else {
                    wac[n].z = pack_bf(e0, e1); wac[n].w = pack_bf(e2, e3);
                }
            }
        }

        // retire staging regs into the OTHER buffer (safe: all reads of that
        // buffer completed before the last barrier)
        if (pre) {
            *(ushort8*)&ldsK[cur ^ 1][sk_off] = nK;
            uint32x4 v4 = *(uint32x4*)&nV;
            *(uint2*)&ldsV[cur ^ 1][sv_b0] = make_uint2(v4.x, v4.y);
            *(uint2*)&ldsV[cur ^ 1][sv_b1] = make_uint2(v4.z, v4.w);
        }

        // V^T fragments (A[ch][pos]) from LDS (permuted key-positions)
        short8 vf[4];
        #pragma unroll
        for (int mc = 0; mc < 4; ++mc)
            vf[mc] = *(const short8*)&ldsV[cur][(16 * mc + l15) * 40 + quad * 8];

        // O^T += V^T·P^T (K=32): P directly from packed registers
        __builtin_amdgcn_s_setprio(1);
        #pragma unroll
        for (int n = 0; n < 2; ++n) {
            short8 bfr = *(short8*)&wac[n];
            #pragma unroll
            for (int mc = 0; mc < 4; ++mc)
                O[mc][n] = __builtin_amdgcn_mfma_f32_16x16x32_bf16(vf[mc], bfr,
                                                                   O[mc][n], 0, 0, 0);
        }
        __builtin_amdgcn_s_setprio(0);

        __syncthreads();
    }

    #pragma unroll
    for (int n = 0; n < 2; ++n) {       // disjoint key subsets per quad
        lrun[n] += __shfl_xor(lrun[n], 16, 64);
        lrun[n] += __shfl_xor(lrun[n], 32, 64);
    }
    if (quad == 0) {                    // accumulate denominator across p-blocks
        #pragma unroll
        for (int n = 0; n < 2; ++n)
            atomicAdd(&L[(size_t)b * NPIX + qwave + 16 * n + l15], lrun[n]);
    }
    size_t bp = (size_t)b * P + p;
    // pacc[b][p][c][n]: per (n,m,r) scalar 2B stores; across l15 lanes each
    // (m,r) is a 32B contiguous segment -> sector-aligned.
    #pragma unroll
    for (int n = 0; n < 2; ++n) {
        int qg = qwave + 16 * n + l15;
        #pragma unroll
        for (int m = 0; m < 4; ++m) {
            #pragma unroll
            for (int r = 0; r < 4; ++r) {
                int c = 16 * m + quad * 4 + r;
                pacc[(bp * NCH + c) * NPIX + qg] = f2bf_rne(O[m][n][r]);
            }
        }
    }
}

// ---------------------------------------------------------------------------
// Kernel 4: fully-coalesced combine with inline normalization. thread =
// (b, c, 8-n segment): o[n] = sum_p pacc[b][p][c][n], out = x + 0.2/L * o.
// ---------------------------------------------------------------------------
__global__ void k_combine(const float* __restrict__ x, const float* __restrict__ L,
                          const ushort* __restrict__ pacc, float* __restrict__ out,
                          int P) {
    int gid = blockIdx.x * blockDim.x + threadIdx.x;   // (b*NCH + c)*1152 + seg
    if (gid >= BB * NCH * (NPIX / 8)) return;
    int seg = gid % (NPIX / 8);
    int bc  = gid / (NPIX / 8);
    int b = bc / NCH;
    int n0 = seg * 8;
    float o[8] = {0.f, 0.f, 0.f, 0.f, 0.f, 0.f, 0.f, 0.f};
    for (int p = 0; p < P; ++p) {
        ushort8 t = *(const ushort8*)(pacc +
            (((size_t)b * P + p) * NCH + (bc % NCH)) * NPIX + n0);
        #pragma unroll
        for (int e = 0; e < 8; ++e) o[e] += bf2f(t[e]);
    }
    const float* lv = L + (size_t)b * NPIX + n0;
    const float* xb = x + (size_t)bc * NPIX + n0;
    float* ob = out + (size_t)bc * NPIX + n0;
    #pragma unroll
    for (int e = 0; e < 8; ++e)
        ob[e] = fmaf(0.2f / lv[e], o[e], xb[e]);
}

// ---------------------------------------------------------------------------
extern "C" void kernel_launch(void* const* d_in, const int* in_sizes, int n_in,
                              void* d_out, int out_size, void* d_ws, size_t ws_size,
                              hipStream_t stream) {
    const float* x      = (const float*)d_in[0];
    const float* w_red  = (const float*)d_in[1];
    const float* b_red  = (const float*)d_in[2];
    const float* w_dil  = (const float*)d_in[3];
    const float* b_dil  = (const float*)d_in[4];
    const float* w_fuse = (const float*)d_in[5];
    const float* b_fuse = (const float*)d_in[6];
    float* out = (float*)d_out;

    // ws: xred f32 | FT bf16 | tok bf16 | tokTt bf16 | L f32 | pacc bf16
    const size_t XRED_N = (size_t)BB * INNER * NPIX;
    const size_t FT_N   = (size_t)64 * TOTPIX;
    const size_t TOK_N  = (size_t)BB * NPIX * NCH;
    const size_t HEAD_B = XRED_N * 4 + (FT_N + 2 * TOK_N) * 2 + TOTPIX * 4;
    int P = 0;
    // KP = NPIX/P must be a multiple of 32 (tile size). P=16 -> KP=576,
    // grid 2304 = 3 exact generations at the measured 3-blocks/CU capacity.
    const int cands[5] = {16, 8, 4, 2, 1};
    for (int ci = 0; ci < 5; ++ci) {
        int cp = cands[ci];
        size_t need = HEAD_B + (size_t)BB * cp * NPIX * NCH * 2;
        if (ws_size >= need) { P = cp; break; }
    }
    if (P == 0) return;

    float*  xred  = (float*)d_ws;
    ushort* FT    = (ushort*)(xred + XRED_N);
    ushort* tok   = FT + FT_N;
    ushort* tokTt = tok + TOK_N;
    float*  L     = (float*)(tokTt + TOK_N);
    ushort* pacc  = (ushort*)(L + TOTPIX);

    k_reduce <<<TOTPIX / 64, 256, 0, stream>>>(x, w_red, b_red, xred);
    k_feat   <<<9 * TOTPIX / 256, 256, 0, stream>>>(xred, w_dil, b_dil, FT);
    hipMemsetAsync(L, 0, TOTPIX * sizeof(float), stream);
    k_fuse   <<<TOTPIX / 64, 256, 0, stream>>>(FT, w_fuse, b_fuse, tok, tokTt);
    k_attn   <<<BB * P * (NPIX / 128), 256, 0, stream>>>(tok, tokTt, L, pacc,
                                                         P, NPIX / P);
    k_combine<<<(BB * NCH * (NPIX / 8) + 255) / 256, 256, 0, stream>>>(x, L, pacc,
                                                                       out, P);
}